// Round 7
// baseline (4992.031 us; speedup 1.0000x reference)
//
#include <hip/hip_runtime.h>
#include <cstdint>
#include <cstddef>

using u16 = unsigned short;
typedef short short8 __attribute__((ext_vector_type(8)));
typedef short short4v __attribute__((ext_vector_type(4)));
typedef float f32x4 __attribute__((ext_vector_type(4)));

#define LN_EPS 1e-5f
#define ATT_BETA 0.125f

__device__ __forceinline__ u16 f2bf(float f){
  uint32_t u = __float_as_uint(f);
  u += 0x7fffu + ((u >> 16) & 1u);
  return (u16)(u >> 16);
}
__device__ __forceinline__ float bf2f(u16 h){
  return __uint_as_float(((uint32_t)h) << 16);
}
__device__ __forceinline__ float wred_sum(float v){
  #pragma unroll
  for(int o=32;o;o>>=1) v += __shfl_xor(v,o,64);
  return v;
}
__device__ __forceinline__ void async16(const void* g, void* l){
  __builtin_amdgcn_global_load_lds((const __attribute__((address_space(1))) void*)g,
                                   (__attribute__((address_space(3))) void*)l, 16, 0, 0);
}

// ---------------- generic bf16 MFMA GEMM: C[M,N] = A[M,K] * B[N,K]^T (B row stride ldb) -------
// EPI: 1=bf16+relu out (row stride ldc), 2=t += alpha*acc (plain RMW), 3=encode epilogue,
//      4=decode epilogue
// ASPL: A operand split: k<768 from A, k>=768 from A2 (both row stride 768)
template<int EPI, int ASPL>
__global__ __launch_bounds__(256)
void gemm_bt(const u16* __restrict__ A, const u16* __restrict__ A2,
             const u16* __restrict__ B,
             u16* __restrict__ Cb, float* __restrict__ Cf,
             int M, int N, int K, int ldb, int ldc,
             const float* __restrict__ aux0, const float* __restrict__ aux1,
             const float* __restrict__ araw, int blk)
{
  __shared__ u16 lA[128*32];
  __shared__ u16 lB[128*32];
  int tid = threadIdx.x;
  int w = tid >> 6, l = tid & 63;
  int wm = w >> 1, wn = w & 1;
  int m0 = blockIdx.y * 128, n0 = blockIdx.x * 128;
  int lr = l >> 2;           // row within 16-row chunk
  int lc = (l & 3) * 8;      // col (elements) within 32-wide K slab
  f32x4 acc[4][4];
  #pragma unroll
  for(int i=0;i<4;i++)
    #pragma unroll
    for(int j=0;j<4;j++) acc[i][j] = (f32x4){0.f,0.f,0.f,0.f};
  int fm = l & 15, fq = (l >> 4) * 8;

  for(int kt=0; kt<K; kt+=32){
    __syncthreads();
    const u16* Asrc = A; int kcol = kt;
    if(ASPL){ if(kt >= 768){ Asrc = A2; kcol = kt - 768; } }
    int lda = ASPL ? 768 : K;
    #pragma unroll
    for(int c=0;c<2;c++){
      int rr = (w*2+c)*16;
      int ga = m0 + rr + lr; if(ga > M-1) ga = M-1;
      async16(Asrc + (size_t)ga*lda + kcol + lc, &lA[rr*32]);
      int gb = n0 + rr + lr; if(gb > N-1) gb = N-1;
      async16(B + (size_t)gb*ldb + kt + lc, &lB[rr*32]);
    }
    __syncthreads();
    short8 af[4], bfv[4];
    #pragma unroll
    for(int i=0;i<4;i++) af[i]  = *(const short8*)&lA[(wm*64 + i*16 + fm)*32 + fq];
    #pragma unroll
    for(int j=0;j<4;j++) bfv[j] = *(const short8*)&lB[(wn*64 + j*16 + fm)*32 + fq];
    #pragma unroll
    for(int i=0;i<4;i++)
      #pragma unroll
      for(int j=0;j<4;j++)
        acc[i][j] = __builtin_amdgcn_mfma_f32_16x16x32_bf16(af[i], bfv[j], acc[i][j], 0, 0, 0);
  }

  float alpha = 0.f;
  if(EPI==2) alpha = log1pf(__expf(araw[blk]));

  #pragma unroll
  for(int i=0;i<4;i++){
    int row_b = m0 + wm*64 + i*16 + (l>>4)*4;
    #pragma unroll
    for(int j=0;j<4;j++){
      int col = n0 + wn*64 + j*16 + (l&15);
      #pragma unroll
      for(int r=0;r<4;r++){
        int row = row_b + r;
        if(row >= M) continue;
        float v = acc[i][j][r];
        if(EPI==1){
          Cb[(size_t)row*ldc + col] = f2bf(v > 0.f ? v : 0.f);
        } else if(EPI==2){
          Cf[(size_t)row*768 + col] += alpha * v;
        } else if(EPI==3){
          int pb = row / 196, pn = row - pb*196;
          Cf[((size_t)pb*197 + 1 + pn)*768 + col] = v + aux0[col] + aux1[(size_t)(1+pn)*768 + col];
        } else { // EPI==4
          int pb = row / 197, rr2 = row - pb*197;
          if(rr2 > 0) Cf[((size_t)pb*196 + rr2 - 1)*768 + col] = v + aux0[col];
        }
      }
    }
  }
}

// ---------------- LN: mode 0 = EnergyLN (scalar gamma + per-dim bias), 1 = final LN ----------
// vectorized: 192 threads x f32x4 loads (768 = 192*4)
__global__ __launch_bounds__(256)
void norm_k(const float* __restrict__ t, u16* __restrict__ out,
            const float* __restrict__ gv, const float* __restrict__ bv, int blk, int mode)
{
  __shared__ float r1[4], r2[4];
  int row = blockIdx.x;
  const float* tr = t + (size_t)row*768;
  int tid = threadIdx.x, w = tid>>6, l = tid&63;
  f32x4 v = (f32x4){0.f,0.f,0.f,0.f};
  float s=0.f, s2=0.f;
  if(tid < 192){
    v = ((const f32x4*)tr)[tid];
    s  = v[0]+v[1]+v[2]+v[3];
    s2 = v[0]*v[0]+v[1]*v[1]+v[2]*v[2]+v[3]*v[3];
  }
  s = wred_sum(s); s2 = wred_sum(s2);
  if(l==0){ r1[w]=s; r2[w]=s2; }
  __syncthreads();
  s  = r1[0]+r1[1]+r1[2]+r1[3];
  s2 = r2[0]+r2[1]+r2[2]+r2[3];
  float mu  = s * (1.0f/768.0f);
  float var = s2 * (1.0f/768.0f) - mu*mu;
  float rs  = rsqrtf(var + LN_EPS);
  u16* orow = out + (size_t)row*768;
  if(tid < 192){
    short4v o;
    if(mode==0){
      float gm = gv[blk];
      const float* bb = bv + blk*768;
      #pragma unroll
      for(int c=0;c<4;c++) o[c] = (short)f2bf((v[c]-mu)*rs*gm + bb[tid*4+c]);
    } else {
      #pragma unroll
      for(int c=0;c<4;c++) o[c] = (short)f2bf((v[c]-mu)*rs*gv[tid*4+c] + bv[tid*4+c]);
    }
    ((short4v*)orow)[tid] = o;
  }
}

// ---------------- fused QK-projection + attention per (b,h), 16 waves -------------------------
// Grid 768 x 1024 threads, __launch_bounds__(1024,4): LDS caps at 1 block/CU, so 16 waves gives
// 4 waves/SIMD (R6 had 2/SIMD at 200us, latency-bound: MfmaUtil 9%, VALUBusy 26%).
// Phase A (GEMM-anatomy): g slabs [208][32] double-buffered via global_load_lds (aliased on the
// P/PT region); wave = (half Q/K = w>>3) x (row-group w&7, tiles {2,2,2,2,2,1,1,1}); 4 weight
// B-frags in registers with next-kt prefetch. Outputs written to LDS row-major ([208][72]) and
// transposed ([64][232]) straight from accumulators.
// Phase B: scores split over 16 waves (13 n-tiles {2,...,1} x q-half); Gq on waves 0-7 (one
// 16x16 tile each), Gk on waves 8-15 (13 j-tiles {2,...,1}) -- disjoint-wave overlap of the
// two GEMMs. All Q/K/QT/KT reads from LDS.
__global__ __launch_bounds__(1024, 4)
void attn_fused(const u16* __restrict__ g, const u16* __restrict__ Wqk,
                u16* __restrict__ GqO, u16* __restrict__ GkO)
{
  __shared__ u16 smem[76800];          // 153,600 B
  __shared__ float SredS[2][8][16];
  u16* Qlds = smem;                    // [208][72]  29,952 B
  u16* Klds = smem + 14976;            // [208][72]
  u16* QTl  = smem + 29952;            // [64][232]  29,696 B
  u16* KTl  = smem + 44800;            // [64][232]
  u16* P    = smem + 59648;            // [32][256]  16,384 B (phase B)
  u16* PT   = smem + 67840;            // [224][40]  17,920 B (phase B)
  u16* lg   = smem + 59648;            // phase-A alias: [2][208*32] = 26,624 B <= P+PT region

  int bhw = blockIdx.x;
  int bh = (bhw & 7)*96 + (bhw >> 3);   // bijective XCD chunk swizzle (768 % 8 == 0)
  int b = bh/12, h = bh - b*12;
  const u16* grows = g + (size_t)b*197*768;
  u16* Qg = GqO + (size_t)b*197*768 + h*64;
  u16* Kg = GkO + (size_t)b*197*768 + h*64;
  int tid = threadIdx.x, w = tid>>6, l = tid&63;
  int lane16 = l & 15, quad = l >> 4;

  // zero transposed-pad cols 208..231 (read by Gq kt=6 / Gk st=6 upper quads)
  for(int idx=tid; idx<64*24; idx+=1024){
    int z = idx/24, c = 208 + (idx - (idx/24)*24);
    QTl[z*232 + c] = 0; KTl[z*232 + c] = 0;
  }

  // ---- phase A: projection, staged. ----
  {
    int half = w >> 3;                   // 0=Q (waves 0-7), 1=K (waves 8-15)
    int wsub = w & 7;                    // rt row-group: {2,2,2,2,2,1,1,1} over 13
    int rt0 = (wsub<5) ? 2*wsub : 10+(wsub-5);
    int rtn = (wsub<5) ? 2 : 1;
    const u16* Wb = Wqk + (size_t)half*589824 + (size_t)(h*64)*768;
    u16* Lr = half ? Klds : Qlds;
    u16* Lt = half ? KTl  : QTl;
    f32x4 acc[2][4];
    #pragma unroll
    for(int i=0;i<2;i++)
      #pragma unroll
      for(int z=0;z<4;z++) acc[i][z] = (f32x4){0.f,0.f,0.f,0.f};

    // slab staging: 208 rows x 32 cols bf16 = 832 16B-chunks; chunk tid -> (row=tid>>2, c4=tid&3)
    #define STAGE_G(bufi, ktv) do{                                                    \
      if(tid < 832){ int rw = tid>>2, c4 = tid&3; int r2 = rw>196?196:rw;             \
        async16(grows + (size_t)r2*768 + (ktv)*32 + c4*8, lg + (bufi)*6656 + tid*8);} \
    }while(0)

    short8 bq[4], bqn[4];
    #pragma unroll
    for(int z=0;z<4;z++) bq[z] = *(const short8*)(Wb + (size_t)(z*16+lane16)*768 + quad*8);
    STAGE_G(0, 0);
    int buf = 0;
    for(int kt=0; kt<24; kt++){
      __syncthreads();                  // drains vmcnt -> slab[buf] ready
      if(kt < 23){
        STAGE_G(buf^1, kt+1);
        #pragma unroll
        for(int z=0;z<4;z++)
          bqn[z] = *(const short8*)(Wb + (size_t)(z*16+lane16)*768 + (kt+1)*32 + quad*8);
      }
      const u16* lb = lg + buf*6656;
      #pragma unroll
      for(int i=0;i<2;i++) if(i<rtn){
        short8 af = *(const short8*)(lb + (size_t)((rt0+i)*16 + lane16)*32 + quad*8);
        #pragma unroll
        for(int z=0;z<4;z++)
          acc[i][z] = __builtin_amdgcn_mfma_f32_16x16x32_bf16(af, bq[z], acc[i][z],0,0,0);
      }
      #pragma unroll
      for(int z=0;z<4;z++) bq[z] = bqn[z];
      buf ^= 1;
    }
    #undef STAGE_G

    #pragma unroll
    for(int i=0;i<2;i++) if(i<rtn)
      #pragma unroll
      for(int z=0;z<4;z++)
        #pragma unroll
        for(int r=0;r<4;r++){
          int q  = (rt0+i)*16 + quad*4 + r;   // D-layout: row=(l>>4)*4+r
          int zz = z*16 + lane16;             //           col=l&15
          u16 hv = f2bf(acc[i][z][r]);
          Lr[q*72   + zz] = hv;
          Lt[zz*232 + q ] = hv;
        }
  }
  __syncthreads();

  // zero P logical cols 208..223 once (never overwritten: P data writes have j<208; read by
  // Gq kt=6 upper quads). Separated from first Gq read by the stripe-loop barriers.
  if(tid < 512){
    int q = tid>>4, j = 208 + (tid&15);
    P[q*256 + 8*((j>>3)^(q&7)) + (j&7)] = 0;
  }

  // ---- phase B: attention body, LDS-sourced, 16-wave split
  int smt = w & 1, snh = w >> 1;                // scores: q-half x 8 col-groups
  int ncnt = (snh<5) ? 2 : 1;                   // n-tiles {2,2,2,2,2,1,1,1} over 13
  int nt0s = (snh<5) ? 2*snh : 10+(snh-5);
  int w8 = w - 8;                               // Gk waves
  int jt0 = 0, jn = 0;
  if(w >= 8){ jt0 = (w8<5) ? 2*w8 : 10+(w8-5); jn = (w8<5) ? 2 : 1; }

  f32x4 gk[2][4];
  #pragma unroll
  for(int a=0;a<2;a++)
    #pragma unroll
    for(int n2=0;n2<4;n2++) gk[a][n2] = (f32x4){0.f,0.f,0.f,0.f};

  for(int st=0; st<7; st++){
    int q0 = st*32;
    __syncthreads();   // protect P/PT/SredS rewrite vs previous stripe readers
    int qa = q0 + 16*smt + lane16; if(qa > 196) qa = 196;
    short8 a0 = *(const short8*)&Qlds[qa*72 + quad*8];
    short8 a1 = *(const short8*)&Qlds[qa*72 + 32 + quad*8];
    f32x4 sa[2];
    #pragma unroll
    for(int ni=0;ni<2;ni++) sa[ni] = (f32x4){0.f,0.f,0.f,0.f};
    for(int ni=0; ni<ncnt; ni++){
      int jb = (nt0s+ni)*16 + lane16; if(jb > 196) jb = 196;
      short8 b0 = *(const short8*)&Klds[jb*72 + quad*8];
      short8 b1 = *(const short8*)&Klds[jb*72 + 32 + quad*8];
      sa[ni] = __builtin_amdgcn_mfma_f32_16x16x32_bf16(a0, b0, sa[ni],0,0,0);
      sa[ni] = __builtin_amdgcn_mfma_f32_16x16x32_bf16(a1, b1, sa[ni],0,0,0);
    }
    for(int ni=0; ni<ncnt; ni++){
      if((nt0s+ni)*16 + lane16 > 196){
        sa[ni][0]=-3e38f; sa[ni][1]=-3e38f; sa[ni][2]=-3e38f; sa[ni][3]=-3e38f;
      }
    }
    // no-max softmax (beta=0.125, logits bounded; arg clamped)
    float ss[4] = {0.f,0.f,0.f,0.f};
    for(int ni=0; ni<ncnt; ni++)
      #pragma unroll
      for(int r=0;r<4;r++){
        float e = __expf(fminf(ATT_BETA*sa[ni][r], 80.f));
        sa[ni][r] = e; ss[r] += e;
      }
    #pragma unroll
    for(int o=1;o<16;o<<=1)
      #pragma unroll
      for(int r=0;r<4;r++) ss[r] += __shfl_xor(ss[r], o, 64);
    if(lane16==0){
      #pragma unroll
      for(int r=0;r<4;r++) SredS[smt][snh][quad*4+r] = ss[r];
    }
    __syncthreads();
    float inv[4];
    #pragma unroll
    for(int r=0;r<4;r++){
      float sr = 0.f;
      #pragma unroll
      for(int pp=0; pp<8; pp++) sr += SredS[smt][pp][quad*4+r];
      inv[r] = 1.f/sr;
    }
    // write P (swizzled) + PT (packed b64); rows q>196 forced 0
    for(int ni=0; ni<ncnt; ni++){
      int j = (nt0s+ni)*16 + lane16;
      short4v pk;
      #pragma unroll
      for(int r=0;r<4;r++){
        int q = 16*smt + quad*4 + r;
        float val = (q0 + q <= 196) ? sa[ni][r]*inv[r] : 0.f;
        u16 hv = f2bf(val);
        P[q*256 + 8*((j>>3)^(q&7)) + (j&7)] = hv;
        pk[r] = (short)hv;
      }
      *(short4v*)&PT[j*40 + 16*smt + 4*quad] = pk;
    }
    __syncthreads();
    // ---- Gq = P K : waves 0-7, one 16x16 tile each (mt x nh), B-frags from KTl
    if(w < 8){
      int mt = w & 1, nh = w >> 1;
      f32x4 gq = (f32x4){0.f,0.f,0.f,0.f};
      int qrow = 16*mt + lane16;
      int z = nh*16 + lane16;
      for(int kt=0; kt<7; kt++){
        short8 af = *(const short8*)&P[qrow*256 + 8*((4*kt+quad)^(qrow&7))];
        short8 bf8 = *(const short8*)&KTl[z*232 + kt*32 + quad*8];
        gq = __builtin_amdgcn_mfma_f32_16x16x32_bf16(af, bf8, gq,0,0,0);
      }
      #pragma unroll
      for(int r=0;r<4;r++){
        int qg2 = q0 + 16*mt + quad*4 + r;
        if(qg2 <= 196) Qg[(size_t)qg2*768 + nh*16 + lane16] = f2bf(gq[r]);
      }
    }
    // ---- Gk accumulate: waves 8-15, A-frags from PT, B-frags from QTl
    if(jn){
      short8 bq2[4];
      #pragma unroll
      for(int n2=0;n2<4;n2++)
        bq2[n2] = *(const short8*)&QTl[(n2*16+lane16)*232 + q0 + quad*8];
      for(int ji=0; ji<jn; ji++){
        int j = (jt0+ji)*16 + lane16;
        short8 af = *(const short8*)&PT[j*40 + quad*8];
        #pragma unroll
        for(int n2=0;n2<4;n2++)
          gk[ji][n2] = __builtin_amdgcn_mfma_f32_16x16x32_bf16(af, bq2[n2], gk[ji][n2],0,0,0);
      }
    }
  }
  __syncthreads();
  for(int ji=0; ji<jn; ji++){
    int jt = jt0 + ji;
    #pragma unroll
    for(int n2=0;n2<4;n2++)
      #pragma unroll
      for(int r=0;r<4;r++){
        int j = jt*16 + quad*4 + r;
        if(j <= 196) Kg[(size_t)j*768 + n2*16 + lane16] = f2bf(gk[ji][n2][r]);
      }
  }
}

// ---------------- small utility kernels ----------------
__global__ void cvt_k(const float* __restrict__ in, u16* __restrict__ out, int n){
  for(int i=blockIdx.x*256+threadIdx.x; i<n; i+=gridDim.x*256) out[i] = f2bf(in[i]);
}

// dst[c*dstride + coff + r] = bf16(src[r*C + c]); R,C multiples of 32
__global__ __launch_bounds__(256)
void tr_k(const float* __restrict__ src, u16* __restrict__ dst, int R, int C, int dstride, int coff){
  __shared__ float tile[32][33];
  int c0 = blockIdx.x*32, r0 = blockIdx.y*32;
  int tx = threadIdx.x & 31, ty = threadIdx.x >> 5;
  for(int i=ty;i<32;i+=8) tile[i][tx] = src[(size_t)(r0+i)*C + c0 + tx];
  __syncthreads();
  for(int i=ty;i<32;i+=8) dst[(size_t)(c0+i)*dstride + coff + r0 + tx] = f2bf(tile[tx][i]);
}

__global__ void fill_cls_k(float* __restrict__ t, const float* __restrict__ cls, const float* __restrict__ pos){
  int b = blockIdx.x;
  for(int i=threadIdx.x;i<768;i+=256) t[(size_t)b*197*768 + i] = cls[i] + pos[i];
}

// ---------------- launch ----------------
extern "C" void kernel_launch(void* const* d_in, const int* in_sizes, int n_in,
                              void* d_out, int out_size, void* d_ws, size_t ws_size,
                              hipStream_t stream){
  const float* x      = (const float*)d_in[0];
  const float* W_enc  = (const float*)d_in[1];
  const float* b_enc  = (const float*)d_in[2];
  const float* cls    = (const float*)d_in[3];
  const float* pos    = (const float*)d_in[4];
  const float* gamma  = (const float*)d_in[5];
  const float* bias   = (const float*)d_in[6];
  const float* Wq     = (const float*)d_in[7];
  const float* Wk     = (const float*)d_in[8];
  const float* Whn    = (const float*)d_in[9];
  const float* araw   = (const float*)d_in[10];
  const float* ln_g   = (const float*)d_in[11];
  const float* ln_b   = (const float*)d_in[12];
  const float* W_dec  = (const float*)d_in[13];
  const float* b_dec  = (const float*)d_in[14];
  float* out = (float*)d_out;
  (void)in_sizes; (void)n_in; (void)out_size;

  const int M  = 64*197;   // 12608
  const int MX = 64*196;   // 12544

  // ---- workspace ----
  char* p = (char*)d_ws;
  float* t   = (float*)p;  p += (size_t)M*768*4;        // 38.7 MB
  u16*   g   = (u16*)p;    p += (size_t)M*768*2;        // 19.4 MB (LN out)
  u16*   Qb  = (u16*)p;    p += (size_t)M*768*2;        // 19.4 MB (Gq out; xb overlay)
  u16*   Kb  = (u16*)p;    p += (size_t)M*768*2;        // 19.4 MB (Gk out; WencT/WdecT overlay)
  size_t base = (size_t)(p - (char*)d_ws);
  if(base > ws_size) return;
  // merged-hopfield hidden buffer (77.46 MB) if it fits, else 2-chunk overlay on Qb/Kb
  u16* hidden; int hop_merged;
  if(base + (size_t)M*3072*2 <= ws_size){ hidden = (u16*)(d_ws) + base/2; hop_merged = 1; }
  else { hidden = Qb; hop_merged = 0; }

  // ---- weights live inside d_out (28.3 MB of 38.5 MB; fully dead before decode write) ----
  u16* Wall = (u16*)d_out;
  u16* Wqkb = Wall;               // 2 x [Wq(768 rows); Wk(768 rows)] x 768
  u16* WqkT = Wall + 2359296;     // 2 x 768 x [WqT | WkT] (stride 1536)
  u16* WhnT = Wall + 4718592;     // 2 x 3072 x 768
  u16* WhnB = Wall + 9437184;     // 2 x 768 x 3072 (row-major, ldb 3072)
  u16* xb    = Qb;                // encode-time overlay
  u16* WencT = Kb;                // encode-time overlay
  u16* WdecT = Kb;                // decode-time overlay

  // ---- weight prep ----
  for(int b=0;b<2;b++){
    cvt_k<<<512,256,0,stream>>>(Wq + (size_t)b*589824, Wqkb + (size_t)b*1179648, 589824);
    cvt_k<<<512,256,0,stream>>>(Wk + (size_t)b*589824, Wqkb + (size_t)b*1179648 + 589824, 589824);
    tr_k<<<dim3(24,24),256,0,stream>>>(Wq + (size_t)b*589824, WqkT + (size_t)b*1179648, 768,768, 1536, 0);
    tr_k<<<dim3(24,24),256,0,stream>>>(Wk + (size_t)b*589824, WqkT + (size_t)b*1179648, 768,768, 1536, 768);
    tr_k<<<dim3(96,24),256,0,stream>>>(Whn + (size_t)b*2359296, WhnT + (size_t)b*2359296, 768,3072, 768, 0);
    cvt_k<<<2048,256,0,stream>>>(Whn + (size_t)b*2359296, WhnB + (size_t)b*2359296, 2359296);
  }

  // ---- encode: t = [cls; x@W_enc + b_enc] + pos ----
  cvt_k<<<1024,256,0,stream>>>(x, xb, MX*768);
  tr_k<<<dim3(24,24),256,0,stream>>>(W_enc, WencT, 768,768, 768, 0);
  fill_cls_k<<<64,256,0,stream>>>(t, cls, pos);
  gemm_bt<3,0><<<dim3(6,98),256,0,stream>>>(xb, nullptr, WencT, nullptr, t,
                                            MX, 768, 768, 768, 768,
                                            b_enc, pos, nullptr, 0);

  // ---- energy-descent blocks ----
  for(int blk=0; blk<2; blk++){
    for(int s=0; s<4; s++){
      norm_k<<<M,256,0,stream>>>(t, g, gamma, bias, blk, 0);
      if(hop_merged){
        gemm_bt<1,0><<<dim3(24,99),256,0,stream>>>(g, nullptr,
            WhnT + (size_t)blk*2359296,
            hidden, nullptr, M, 3072, 768, 768, 3072,
            nullptr, nullptr, nullptr, 0);
        gemm_bt<2,0><<<dim3(6,99),256,0,stream>>>(hidden, nullptr,
            WhnB + (size_t)blk*2359296,
            nullptr, t, M, 768, 3072, 3072, 768,
            nullptr, nullptr, araw, blk);
      } else {
        for(int c=0;c<2;c++){
          gemm_bt<1,0><<<dim3(12,99),256,0,stream>>>(g, nullptr,
              WhnT + (size_t)blk*2359296 + (size_t)c*1536*768,
              hidden, nullptr, M, 1536, 768, 768, 1536,
              nullptr, nullptr, nullptr, 0);
          gemm_bt<2,0><<<dim3(6,99),256,0,stream>>>(hidden, nullptr,
              WhnB + (size_t)blk*2359296 + (size_t)c*1536,
              nullptr, t, M, 768, 1536, 3072, 768,
              nullptr, nullptr, araw, blk);
        }
      }
      // fused QK-projection + attention: reads g + Wqk, writes Gq -> Qb, Gk -> Kb
      attn_fused<<<768,1024,0,stream>>>(g, Wqkb + (size_t)blk*1179648, Qb, Kb);
      // gradient projection (merged K=1536, split-A: A=Gq(Qb), A2=Gk(Kb))
      gemm_bt<2,1><<<dim3(6,99),256,0,stream>>>(Qb, Kb, WqkT + (size_t)blk*1179648,
            nullptr, t, M, 768, 1536, 1536, 768,
            nullptr, nullptr, araw, blk);
    }
  }

  // ---- decode: LN -> GEMM -> drop CLS ----
  tr_k<<<dim3(24,24),256,0,stream>>>(W_dec, WdecT, 768,768, 768, 0);
  norm_k<<<M,256,0,stream>>>(t, g, ln_g, ln_b, 0, 1);
  gemm_bt<4,0><<<dim3(6,99),256,0,stream>>>(g, nullptr, WdecT, nullptr, out,
                                            M, 768, 768, 768, 768,
                                            b_dec, nullptr, nullptr, 0);
}

// Round 8
// 4290.067 us; speedup vs baseline: 1.1636x; 1.1636x over previous
//
#include <hip/hip_runtime.h>
#include <cstdint>
#include <cstddef>

using u16 = unsigned short;
typedef short short8 __attribute__((ext_vector_type(8)));
typedef short short4v __attribute__((ext_vector_type(4)));
typedef float f32x4 __attribute__((ext_vector_type(4)));

#define LN_EPS 1e-5f
#define ATT_BETA 0.125f

__device__ __forceinline__ u16 f2bf(float f){
  uint32_t u = __float_as_uint(f);
  u += 0x7fffu + ((u >> 16) & 1u);
  return (u16)(u >> 16);
}
__device__ __forceinline__ float bf2f(u16 h){
  return __uint_as_float(((uint32_t)h) << 16);
}
__device__ __forceinline__ float wred_sum(float v){
  #pragma unroll
  for(int o=32;o;o>>=1) v += __shfl_xor(v,o,64);
  return v;
}
__device__ __forceinline__ void async16(const void* g, void* l){
  __builtin_amdgcn_global_load_lds((const __attribute__((address_space(1))) void*)g,
                                   (__attribute__((address_space(3))) void*)l, 16, 0, 0);
}

// ---------------- generic bf16 MFMA GEMM: C[M,N] = A[M,K] * B[N,K]^T (B row stride ldb) -------
// EPI: 1=bf16+relu out (row stride ldc), 2=t += alpha*acc (plain RMW), 3=encode epilogue,
//      4=decode epilogue
// ASPL: A operand split: k<768 from A, k>=768 from A2 (both row stride 768)
template<int EPI, int ASPL>
__global__ __launch_bounds__(256)
void gemm_bt(const u16* __restrict__ A, const u16* __restrict__ A2,
             const u16* __restrict__ B,
             u16* __restrict__ Cb, float* __restrict__ Cf,
             int M, int N, int K, int ldb, int ldc,
             const float* __restrict__ aux0, const float* __restrict__ aux1,
             const float* __restrict__ araw, int blk)
{
  __shared__ u16 lA[128*32];
  __shared__ u16 lB[128*32];
  int tid = threadIdx.x;
  int w = tid >> 6, l = tid & 63;
  int wm = w >> 1, wn = w & 1;
  int m0 = blockIdx.y * 128, n0 = blockIdx.x * 128;
  int lr = l >> 2;           // row within 16-row chunk
  int lc = (l & 3) * 8;      // col (elements) within 32-wide K slab
  f32x4 acc[4][4];
  #pragma unroll
  for(int i=0;i<4;i++)
    #pragma unroll
    for(int j=0;j<4;j++) acc[i][j] = (f32x4){0.f,0.f,0.f,0.f};
  int fm = l & 15, fq = (l >> 4) * 8;

  for(int kt=0; kt<K; kt+=32){
    __syncthreads();
    const u16* Asrc = A; int kcol = kt;
    if(ASPL){ if(kt >= 768){ Asrc = A2; kcol = kt - 768; } }
    int lda = ASPL ? 768 : K;
    #pragma unroll
    for(int c=0;c<2;c++){
      int rr = (w*2+c)*16;
      int ga = m0 + rr + lr; if(ga > M-1) ga = M-1;
      async16(Asrc + (size_t)ga*lda + kcol + lc, &lA[rr*32]);
      int gb = n0 + rr + lr; if(gb > N-1) gb = N-1;
      async16(B + (size_t)gb*ldb + kt + lc, &lB[rr*32]);
    }
    __syncthreads();
    short8 af[4], bfv[4];
    #pragma unroll
    for(int i=0;i<4;i++) af[i]  = *(const short8*)&lA[(wm*64 + i*16 + fm)*32 + fq];
    #pragma unroll
    for(int j=0;j<4;j++) bfv[j] = *(const short8*)&lB[(wn*64 + j*16 + fm)*32 + fq];
    #pragma unroll
    for(int i=0;i<4;i++)
      #pragma unroll
      for(int j=0;j<4;j++)
        acc[i][j] = __builtin_amdgcn_mfma_f32_16x16x32_bf16(af[i], bfv[j], acc[i][j], 0, 0, 0);
  }

  float alpha = 0.f;
  if(EPI==2) alpha = log1pf(__expf(araw[blk]));

  #pragma unroll
  for(int i=0;i<4;i++){
    int row_b = m0 + wm*64 + i*16 + (l>>4)*4;
    #pragma unroll
    for(int j=0;j<4;j++){
      int col = n0 + wn*64 + j*16 + (l&15);
      #pragma unroll
      for(int r=0;r<4;r++){
        int row = row_b + r;
        if(row >= M) continue;
        float v = acc[i][j][r];
        if(EPI==1){
          Cb[(size_t)row*ldc + col] = f2bf(v > 0.f ? v : 0.f);
        } else if(EPI==2){
          Cf[(size_t)row*768 + col] += alpha * v;
        } else if(EPI==3){
          int pb = row / 196, pn = row - pb*196;
          Cf[((size_t)pb*197 + 1 + pn)*768 + col] = v + aux0[col] + aux1[(size_t)(1+pn)*768 + col];
        } else { // EPI==4
          int pb = row / 197, rr2 = row - pb*197;
          if(rr2 > 0) Cf[((size_t)pb*196 + rr2 - 1)*768 + col] = v + aux0[col];
        }
      }
    }
  }
}

// ---------------- LN: mode 0 = EnergyLN (scalar gamma + per-dim bias), 1 = final LN ----------
// vectorized: 192 threads x f32x4 loads (768 = 192*4)
__global__ __launch_bounds__(256)
void norm_k(const float* __restrict__ t, u16* __restrict__ out,
            const float* __restrict__ gv, const float* __restrict__ bv, int blk, int mode)
{
  __shared__ float r1[4], r2[4];
  int row = blockIdx.x;
  const float* tr = t + (size_t)row*768;
  int tid = threadIdx.x, w = tid>>6, l = tid&63;
  f32x4 v = (f32x4){0.f,0.f,0.f,0.f};
  float s=0.f, s2=0.f;
  if(tid < 192){
    v = ((const f32x4*)tr)[tid];
    s  = v[0]+v[1]+v[2]+v[3];
    s2 = v[0]*v[0]+v[1]*v[1]+v[2]*v[2]+v[3]*v[3];
  }
  s = wred_sum(s); s2 = wred_sum(s2);
  if(l==0){ r1[w]=s; r2[w]=s2; }
  __syncthreads();
  s  = r1[0]+r1[1]+r1[2]+r1[3];
  s2 = r2[0]+r2[1]+r2[2]+r2[3];
  float mu  = s * (1.0f/768.0f);
  float var = s2 * (1.0f/768.0f) - mu*mu;
  float rs  = rsqrtf(var + LN_EPS);
  u16* orow = out + (size_t)row*768;
  if(tid < 192){
    short4v o;
    if(mode==0){
      float gm = gv[blk];
      const float* bb = bv + blk*768;
      #pragma unroll
      for(int c=0;c<4;c++) o[c] = (short)f2bf((v[c]-mu)*rs*gm + bb[tid*4+c]);
    } else {
      #pragma unroll
      for(int c=0;c<4;c++) o[c] = (short)f2bf((v[c]-mu)*rs*gv[tid*4+c] + bv[tid*4+c]);
    }
    ((short4v*)orow)[tid] = o;
  }
}

// ---------------- fused QK-projection + attention per (b,h), 8 waves --------------------------
// Grid 768 x 512 threads, __launch_bounds__(512,2). R7 showed 16 waves REGRESSES (barrier-
// serialized kernel: doubling waves/barrier while halving per-wave work lost 60%); 8 waves
// at 2/SIMD is the sweet spot (200us).
// Phase A (GEMM-anatomy): g slabs double-buffered via global_load_lds, CHUNK-MAJOR layout
// [4 c4][208 row][8 elem]: dest = base + tid*16B (HW-required linear order), per-lane global
// src remapped (c4=tid/208,row=tid%208) so the af b128 reads hit consecutive 16B per lane ->
// conflict-free (R6's [208][32] row-stride-64B layout was an 8-way conflict, 7.9M cycles).
// wave = (half Q/K) x (rt row-group); 4 weight B-frags in registers with next-kt prefetch.
// Outputs written to LDS row-major ([208][72]) and transposed ([64][232]) from accumulators.
// Phase B: attention body (scores -> no-max softmax -> Gq = P K, Gk += P^T Q over stripes),
// all Q/K/QT/KT reads from LDS.
__global__ __launch_bounds__(512, 2)
void attn_fused(const u16* __restrict__ g, const u16* __restrict__ Wqk,
                u16* __restrict__ GqO, u16* __restrict__ GkO)
{
  __shared__ u16 smem[76800];          // 153,600 B
  __shared__ float SredS[2][4][16];
  u16* Qlds = smem;                    // [208][72]  29,952 B
  u16* Klds = smem + 14976;            // [208][72]
  u16* QTl  = smem + 29952;            // [64][232]  29,696 B
  u16* KTl  = smem + 44800;            // [64][232]
  u16* P    = smem + 59648;            // [32][256]  16,384 B (phase B)
  u16* PT   = smem + 67840;            // [224][40]  17,920 B (phase B)
  u16* lg   = smem + 59648;            // phase-A alias: [2][832*8] = 26,624 B <= P+PT region

  int bhw = blockIdx.x;
  int bh = (bhw & 7)*96 + (bhw >> 3);   // bijective XCD chunk swizzle (768 % 8 == 0)
  int b = bh/12, h = bh - b*12;
  const u16* grows = g + (size_t)b*197*768;
  u16* Qg = GqO + (size_t)b*197*768 + h*64;
  u16* Kg = GkO + (size_t)b*197*768 + h*64;
  int tid = threadIdx.x, w = tid>>6, l = tid&63;
  int lane16 = l & 15, quad = l >> 4;

  // zero transposed-pad cols 208..231 (read by Gq kt=6 / Gk st=6 upper quads)
  for(int idx=tid; idx<64*24; idx+=512){
    int z = idx/24, c = 208 + (idx - (idx/24)*24);
    QTl[z*232 + c] = 0; KTl[z*232 + c] = 0;
  }

  // ---- phase A: projection, staged. ----
  {
    int half = w >> 2;                   // 0=Q, 1=K
    int wsub = w & 3;                    // rt row-group
    int rt0 = (wsub==0) ? 0 : 1 + 3*wsub;
    int rtn = (wsub==0) ? 4 : 3;
    const u16* Wb = Wqk + (size_t)half*589824 + (size_t)(h*64)*768;
    u16* Lr = half ? Klds : Qlds;
    u16* Lt = half ? KTl  : QTl;
    f32x4 acc[4][4];
    #pragma unroll
    for(int i=0;i<4;i++)
      #pragma unroll
      for(int z=0;z<4;z++) acc[i][z] = (f32x4){0.f,0.f,0.f,0.f};

    // chunk-major slab: chunk d in [0,832) holds (c4=d/208, row=d%208) -> elems row, k-sub c4.
    // dest is linear in d (lane order, HW requirement); per-lane global src carries the remap.
    int c40 = tid/208,        r0a = tid - c40*208;        int rr0 = r0a>196?196:r0a;
    int t1  = tid + 512;
    int c41 = t1/208,         r1a = t1  - c41*208;        int rr1 = r1a>196?196:r1a;
    #define STAGE_G(bufi, ktv) do{                                                     \
      async16(grows + (size_t)rr0*768 + (ktv)*32 + c40*8, lg + (bufi)*6656 + tid*8);   \
      if(t1 < 832)                                                                     \
        async16(grows + (size_t)rr1*768 + (ktv)*32 + c41*8, lg + (bufi)*6656 + t1*8);  \
    }while(0)

    short8 bq[4], bqn[4];
    #pragma unroll
    for(int z=0;z<4;z++) bq[z] = *(const short8*)(Wb + (size_t)(z*16+lane16)*768 + quad*8);
    STAGE_G(0, 0);
    int buf = 0;
    for(int kt=0; kt<24; kt++){
      __syncthreads();                  // drains vmcnt -> slab[buf] ready
      if(kt < 23){
        STAGE_G(buf^1, kt+1);
        #pragma unroll
        for(int z=0;z<4;z++)
          bqn[z] = *(const short8*)(Wb + (size_t)(z*16+lane16)*768 + (kt+1)*32 + quad*8);
      }
      const u16* lb = lg + buf*6656;
      #pragma unroll
      for(int i=0;i<4;i++) if(i<rtn){
        // chunk-major read: chunk = quad*208 + row -> consecutive lanes at consecutive 16B
        short8 af = *(const short8*)(lb + ((size_t)(quad*208 + (rt0+i)*16 + lane16))*8);
        #pragma unroll
        for(int z=0;z<4;z++)
          acc[i][z] = __builtin_amdgcn_mfma_f32_16x16x32_bf16(af, bq[z], acc[i][z],0,0,0);
      }
      #pragma unroll
      for(int z=0;z<4;z++) bq[z] = bqn[z];
      buf ^= 1;
    }
    #undef STAGE_G

    #pragma unroll
    for(int i=0;i<4;i++) if(i<rtn)
      #pragma unroll
      for(int z=0;z<4;z++)
        #pragma unroll
        for(int r=0;r<4;r++){
          int q  = (rt0+i)*16 + quad*4 + r;   // D-layout: row=(l>>4)*4+r
          int zz = z*16 + lane16;             //           col=l&15
          u16 hv = f2bf(acc[i][z][r]);
          Lr[q*72   + zz] = hv;
          Lt[zz*232 + q ] = hv;
        }
  }
  __syncthreads();

  // zero P logical cols 208..223 once (never overwritten: P data writes have j<208; read by
  // Gq kt=6 upper quads). Separated from first Gq read by the stripe-loop barriers.
  {
    int q = tid>>4, j = 208 + (tid&15);
    P[q*256 + 8*((j>>3)^(q&7)) + (j&7)] = 0;
  }

  // ---- phase B: attention body, LDS-sourced, 8-wave split
  int mt = w & 1, nh = w >> 1;                  // mt: q-half of stripe; nh: 0..3
  int ncnt = (nh==0) ? 4 : 3;                   // score n-tiles: {4,3,3,3} over 13
  int nt0s = (nh==0) ? 0 : (1 + 3*nh);
  int jt0 = (w<5) ? 2*w : 10+(w-5);             // Gk j-tiles: {2,2,2,2,2,1,1,1}
  int jn  = (w<5) ? 2 : 1;

  f32x4 gk[2][4];
  #pragma unroll
  for(int a=0;a<2;a++)
    #pragma unroll
    for(int n2=0;n2<4;n2++) gk[a][n2] = (f32x4){0.f,0.f,0.f,0.f};

  for(int st=0; st<7; st++){
    int q0 = st*32;
    __syncthreads();   // protect P/PT/SredS rewrite vs previous stripe readers
    int qa = q0 + 16*mt + lane16; if(qa > 196) qa = 196;
    short8 a0 = *(const short8*)&Qlds[qa*72 + quad*8];
    short8 a1 = *(const short8*)&Qlds[qa*72 + 32 + quad*8];
    f32x4 sa[4];
    #pragma unroll
    for(int ni=0;ni<4;ni++) sa[ni] = (f32x4){0.f,0.f,0.f,0.f};
    for(int ni=0; ni<ncnt; ni++){
      int jb = (nt0s+ni)*16 + lane16; if(jb > 196) jb = 196;
      short8 b0 = *(const short8*)&Klds[jb*72 + quad*8];
      short8 b1 = *(const short8*)&Klds[jb*72 + 32 + quad*8];
      sa[ni] = __builtin_amdgcn_mfma_f32_16x16x32_bf16(a0, b0, sa[ni],0,0,0);
      sa[ni] = __builtin_amdgcn_mfma_f32_16x16x32_bf16(a1, b1, sa[ni],0,0,0);
    }
    for(int ni=0; ni<ncnt; ni++){
      if((nt0s+ni)*16 + lane16 > 196){
        sa[ni][0]=-3e38f; sa[ni][1]=-3e38f; sa[ni][2]=-3e38f; sa[ni][3]=-3e38f;
      }
    }
    // no-max softmax (beta=0.125, logits bounded; arg clamped)
    float ss[4] = {0.f,0.f,0.f,0.f};
    for(int ni=0; ni<ncnt; ni++)
      #pragma unroll
      for(int r=0;r<4;r++){
        float e = __expf(fminf(ATT_BETA*sa[ni][r], 80.f));
        sa[ni][r] = e; ss[r] += e;
      }
    #pragma unroll
    for(int o=1;o<16;o<<=1)
      #pragma unroll
      for(int r=0;r<4;r++) ss[r] += __shfl_xor(ss[r], o, 64);
    if(lane16==0){
      #pragma unroll
      for(int r=0;r<4;r++) SredS[mt][nh][quad*4+r] = ss[r];
    }
    __syncthreads();
    float inv[4];
    #pragma unroll
    for(int r=0;r<4;r++)
      inv[r] = 1.f/(SredS[mt][0][quad*4+r] + SredS[mt][1][quad*4+r]
                  + SredS[mt][2][quad*4+r] + SredS[mt][3][quad*4+r]);
    // write P (swizzled) + PT (packed b64); rows q>196 forced 0
    for(int ni=0; ni<ncnt; ni++){
      int j = (nt0s+ni)*16 + lane16;
      short4v pk;
      #pragma unroll
      for(int r=0;r<4;r++){
        int q = 16*mt + quad*4 + r;
        float val = (q0 + q <= 196) ? sa[ni][r]*inv[r] : 0.f;
        u16 hv = f2bf(val);
        P[q*256 + 8*((j>>3)^(q&7)) + (j&7)] = hv;
        pk[r] = (short)hv;
      }
      *(short4v*)&PT[j*40 + 16*mt + 4*quad] = pk;
    }
    __syncthreads();
    // ---- Gq = P K : one 16x16 tile per wave (mt x nh), B-frags from KTl
    {
      f32x4 gq = (f32x4){0.f,0.f,0.f,0.f};
      int qrow = 16*mt + lane16;
      int z = nh*16 + lane16;
      for(int kt=0; kt<7; kt++){
        short8 af = *(const short8*)&P[qrow*256 + 8*((4*kt+quad)^(qrow&7))];
        short8 bf8 = *(const short8*)&KTl[z*232 + kt*32 + quad*8];
        gq = __builtin_amdgcn_mfma_f32_16x16x32_bf16(af, bf8, gq,0,0,0);
      }
      #pragma unroll
      for(int r=0;r<4;r++){
        int qg2 = q0 + 16*mt + quad*4 + r;
        if(qg2 <= 196) Qg[(size_t)qg2*768 + nh*16 + lane16] = f2bf(gq[r]);
      }
    }
    // ---- Gk accumulate: A-frags from PT, B-frags from QTl
    {
      short8 bq2[4];
      #pragma unroll
      for(int n2=0;n2<4;n2++)
        bq2[n2] = *(const short8*)&QTl[(n2*16+lane16)*232 + q0 + quad*8];
      for(int ji=0; ji<jn; ji++){
        int j = (jt0+ji)*16 + lane16;
        short8 af = *(const short8*)&PT[j*40 + quad*8];
        #pragma unroll
        for(int n2=0;n2<4;n2++)
          gk[ji][n2] = __builtin_amdgcn_mfma_f32_16x16x32_bf16(af, bq2[n2], gk[ji][n2],0,0,0);
      }
    }
  }
  __syncthreads();
  for(int ji=0; ji<jn; ji++){
    int jt = jt0 + ji;
    #pragma unroll
    for(int n2=0;n2<4;n2++)
      #pragma unroll
      for(int r=0;r<4;r++){
        int j = jt*16 + quad*4 + r;
        if(j <= 196) Kg[(size_t)j*768 + n2*16 + lane16] = f2bf(gk[ji][n2][r]);
      }
  }
}

// ---------------- small utility kernels ----------------
__global__ void cvt_k(const float* __restrict__ in, u16* __restrict__ out, int n){
  for(int i=blockIdx.x*256+threadIdx.x; i<n; i+=gridDim.x*256) out[i] = f2bf(in[i]);
}

// dst[c*dstride + coff + r] = bf16(src[r*C + c]); R,C multiples of 32
__global__ __launch_bounds__(256)
void tr_k(const float* __restrict__ src, u16* __restrict__ dst, int R, int C, int dstride, int coff){
  __shared__ float tile[32][33];
  int c0 = blockIdx.x*32, r0 = blockIdx.y*32;
  int tx = threadIdx.x & 31, ty = threadIdx.x >> 5;
  for(int i=ty;i<32;i+=8) tile[i][tx] = src[(size_t)(r0+i)*C + c0 + tx];
  __syncthreads();
  for(int i=ty;i<32;i+=8) dst[(size_t)(c0+i)*dstride + coff + r0 + tx] = f2bf(tile[tx][i]);
}

__global__ void fill_cls_k(float* __restrict__ t, const float* __restrict__ cls, const float* __restrict__ pos){
  int b = blockIdx.x;
  for(int i=threadIdx.x;i<768;i+=256) t[(size_t)b*197*768 + i] = cls[i] + pos[i];
}

// ---------------- launch ----------------
extern "C" void kernel_launch(void* const* d_in, const int* in_sizes, int n_in,
                              void* d_out, int out_size, void* d_ws, size_t ws_size,
                              hipStream_t stream){
  const float* x      = (const float*)d_in[0];
  const float* W_enc  = (const float*)d_in[1];
  const float* b_enc  = (const float*)d_in[2];
  const float* cls    = (const float*)d_in[3];
  const float* pos    = (const float*)d_in[4];
  const float* gamma  = (const float*)d_in[5];
  const float* bias   = (const float*)d_in[6];
  const float* Wq     = (const float*)d_in[7];
  const float* Wk     = (const float*)d_in[8];
  const float* Whn    = (const float*)d_in[9];
  const float* araw   = (const float*)d_in[10];
  const float* ln_g   = (const float*)d_in[11];
  const float* ln_b   = (const float*)d_in[12];
  const float* W_dec  = (const float*)d_in[13];
  const float* b_dec  = (const float*)d_in[14];
  float* out = (float*)d_out;
  (void)in_sizes; (void)n_in; (void)out_size;

  const int M  = 64*197;   // 12608
  const int MX = 64*196;   // 12544

  // ---- workspace ----
  char* p = (char*)d_ws;
  float* t   = (float*)p;  p += (size_t)M*768*4;        // 38.7 MB
  u16*   g   = (u16*)p;    p += (size_t)M*768*2;        // 19.4 MB (LN out)
  u16*   Qb  = (u16*)p;    p += (size_t)M*768*2;        // 19.4 MB (Gq out; xb overlay)
  u16*   Kb  = (u16*)p;    p += (size_t)M*768*2;        // 19.4 MB (Gk out; WencT/WdecT overlay)
  size_t base = (size_t)(p - (char*)d_ws);
  if(base > ws_size) return;
  // merged-hopfield hidden buffer (77.46 MB) if it fits, else 2-chunk overlay on Qb/Kb
  u16* hidden; int hop_merged;
  if(base + (size_t)M*3072*2 <= ws_size){ hidden = (u16*)(d_ws) + base/2; hop_merged = 1; }
  else { hidden = Qb; hop_merged = 0; }

  // ---- weights live inside d_out (28.3 MB of 38.5 MB; fully dead before decode write) ----
  u16* Wall = (u16*)d_out;
  u16* Wqkb = Wall;               // 2 x [Wq(768 rows); Wk(768 rows)] x 768
  u16* WqkT = Wall + 2359296;     // 2 x 768 x [WqT | WkT] (stride 1536)
  u16* WhnT = Wall + 4718592;     // 2 x 3072 x 768
  u16* WhnB = Wall + 9437184;     // 2 x 768 x 3072 (row-major, ldb 3072)
  u16* xb    = Qb;                // encode-time overlay
  u16* WencT = Kb;                // encode-time overlay
  u16* WdecT = Kb;                // decode-time overlay

  // ---- weight prep ----
  for(int b=0;b<2;b++){
    cvt_k<<<512,256,0,stream>>>(Wq + (size_t)b*589824, Wqkb + (size_t)b*1179648, 589824);
    cvt_k<<<512,256,0,stream>>>(Wk + (size_t)b*589824, Wqkb + (size_t)b*1179648 + 589824, 589824);
    tr_k<<<dim3(24,24),256,0,stream>>>(Wq + (size_t)b*589824, WqkT + (size_t)b*1179648, 768,768, 1536, 0);
    tr_k<<<dim3(24,24),256,0,stream>>>(Wk + (size_t)b*589824, WqkT + (size_t)b*1179648, 768,768, 1536, 768);
    tr_k<<<dim3(96,24),256,0,stream>>>(Whn + (size_t)b*2359296, WhnT + (size_t)b*2359296, 768,3072, 768, 0);
    cvt_k<<<2048,256,0,stream>>>(Whn + (size_t)b*2359296, WhnB + (size_t)b*2359296, 2359296);
  }

  // ---- encode: t = [cls; x@W_enc + b_enc] + pos ----
  cvt_k<<<1024,256,0,stream>>>(x, xb, MX*768);
  tr_k<<<dim3(24,24),256,0,stream>>>(W_enc, WencT, 768,768, 768, 0);
  fill_cls_k<<<64,256,0,stream>>>(t, cls, pos);
  gemm_bt<3,0><<<dim3(6,98),256,0,stream>>>(xb, nullptr, WencT, nullptr, t,
                                            MX, 768, 768, 768, 768,
                                            b_enc, pos, nullptr, 0);

  // ---- energy-descent blocks ----
  for(int blk=0; blk<2; blk++){
    for(int s=0; s<4; s++){
      norm_k<<<M,256,0,stream>>>(t, g, gamma, bias, blk, 0);
      if(hop_merged){
        gemm_bt<1,0><<<dim3(24,99),256,0,stream>>>(g, nullptr,
            WhnT + (size_t)blk*2359296,
            hidden, nullptr, M, 3072, 768, 768, 3072,
            nullptr, nullptr, nullptr, 0);
        gemm_bt<2,0><<<dim3(6,99),256,0,stream>>>(hidden, nullptr,
            WhnB + (size_t)blk*2359296,
            nullptr, t, M, 768, 3072, 3072, 768,
            nullptr, nullptr, araw, blk);
      } else {
        for(int c=0;c<2;c++){
          gemm_bt<1,0><<<dim3(12,99),256,0,stream>>>(g, nullptr,
              WhnT + (size_t)blk*2359296 + (size_t)c*1536*768,
              hidden, nullptr, M, 1536, 768, 768, 1536,
              nullptr, nullptr, nullptr, 0);
          gemm_bt<2,0><<<dim3(6,99),256,0,stream>>>(hidden, nullptr,
              WhnB + (size_t)blk*2359296 + (size_t)c*1536,
              nullptr, t, M, 768, 1536, 3072, 768,
              nullptr, nullptr, araw, blk);
        }
      }
      // fused QK-projection + attention: reads g + Wqk, writes Gq -> Qb, Gk -> Kb
      attn_fused<<<768,512,0,stream>>>(g, Wqkb + (size_t)blk*1179648, Qb, Kb);
      // gradient projection (merged K=1536, split-A: A=Gq(Qb), A2=Gk(Kb))
      gemm_bt<2,1><<<dim3(6,99),256,0,stream>>>(Qb, Kb, WqkT + (size_t)blk*1179648,
            nullptr, t, M, 768, 1536, 1536, 768,
            nullptr, nullptr, araw, blk);
    }
  }

  // ---- decode: LN -> GEMM -> drop CLS ----
  tr_k<<<dim3(24,24),256,0,stream>>>(W_dec, WdecT, 768,768, 768, 0);
  norm_k<<<M,256,0,stream>>>(t, g, ln_g, ln_b, 0, 1);
  gemm_bt<4,0><<<dim3(6,99),256,0,stream>>>(g, nullptr, WdecT, nullptr, out,
                                            M, 768, 768, 768, 768,
                                            b_dec, nullptr, nullptr, 0);
}

// Round 9
// 4030.765 us; speedup vs baseline: 1.2385x; 1.0643x over previous
//
#include <hip/hip_runtime.h>
#include <cstdint>
#include <cstddef>

using u16 = unsigned short;
typedef short short8 __attribute__((ext_vector_type(8)));
typedef short short4v __attribute__((ext_vector_type(4)));
typedef float f32x4 __attribute__((ext_vector_type(4)));

#define LN_EPS 1e-5f
#define ATT_BETA 0.125f

__device__ __forceinline__ u16 f2bf(float f){
  uint32_t u = __float_as_uint(f);
  u += 0x7fffu + ((u >> 16) & 1u);
  return (u16)(u >> 16);
}
__device__ __forceinline__ float bf2f(u16 h){
  return __uint_as_float(((uint32_t)h) << 16);
}
__device__ __forceinline__ float wred_sum(float v){
  #pragma unroll
  for(int o=32;o;o>>=1) v += __shfl_xor(v,o,64);
  return v;
}
__device__ __forceinline__ void async16(const void* g, void* l){
  __builtin_amdgcn_global_load_lds((const __attribute__((address_space(1))) void*)g,
                                   (__attribute__((address_space(3))) void*)l, 16, 0, 0);
}

// ---------------- generic bf16 MFMA GEMM: C[M,N] = A[M,K] * B[N,K]^T (B row stride ldb) -------
// EPI: 1=bf16+relu out (row stride ldc), 2=t += alpha*acc (plain RMW), 3=encode epilogue,
//      4=decode epilogue
// ASPL: A operand split: k<768 from A, k>=768 from A2 (both row stride 768)
// Block-id XCD swizzle (bijective, m204): round-robin dispatch -> contiguous per-XCD chunks,
// so co-resident blocks on one XCD share the A-slab (196KB, L2-resident) + neighbor B panels.
template<int EPI, int ASPL>
__global__ __launch_bounds__(256)
void gemm_bt(const u16* __restrict__ A, const u16* __restrict__ A2,
             const u16* __restrict__ B,
             u16* __restrict__ Cb, float* __restrict__ Cf,
             int M, int N, int K, int ldb, int ldc,
             const float* __restrict__ aux0, const float* __restrict__ aux1,
             const float* __restrict__ araw, int blk)
{
  __shared__ u16 lA[128*32];
  __shared__ u16 lB[128*32];
  int tid = threadIdx.x;
  int w = tid >> 6, l = tid & 63;
  int wm = w >> 1, wn = w & 1;
  unsigned nwg = gridDim.x*gridDim.y;
  unsigned lin = blockIdx.y*gridDim.x + blockIdx.x;
  unsigned qq = nwg>>3, rr = nwg&7, xcd = lin&7, idx = lin>>3;
  unsigned swz = (xcd<rr ? xcd*(qq+1) : rr*(qq+1) + (xcd-rr)*qq) + idx;
  int m0 = (int)(swz / gridDim.x) * 128, n0 = (int)(swz % gridDim.x) * 128;
  int lr = l >> 2;           // row within 16-row chunk
  int lc = (l & 3) * 8;      // col (elements) within 32-wide K slab
  f32x4 acc[4][4];
  #pragma unroll
  for(int i=0;i<4;i++)
    #pragma unroll
    for(int j=0;j<4;j++) acc[i][j] = (f32x4){0.f,0.f,0.f,0.f};
  int fm = l & 15, fq = (l >> 4) * 8;

  for(int kt=0; kt<K; kt+=32){
    __syncthreads();
    const u16* Asrc = A; int kcol = kt;
    if(ASPL){ if(kt >= 768){ Asrc = A2; kcol = kt - 768; } }
    int lda = ASPL ? 768 : K;
    #pragma unroll
    for(int c=0;c<2;c++){
      int rr2 = (w*2+c)*16;
      int ga = m0 + rr2 + lr; if(ga > M-1) ga = M-1;
      async16(Asrc + (size_t)ga*lda + kcol + lc, &lA[rr2*32]);
      int gb = n0 + rr2 + lr; if(gb > N-1) gb = N-1;
      async16(B + (size_t)gb*ldb + kt + lc, &lB[rr2*32]);
    }
    __syncthreads();
    short8 af[4], bfv[4];
    #pragma unroll
    for(int i=0;i<4;i++) af[i]  = *(const short8*)&lA[(wm*64 + i*16 + fm)*32 + fq];
    #pragma unroll
    for(int j=0;j<4;j++) bfv[j] = *(const short8*)&lB[(wn*64 + j*16 + fm)*32 + fq];
    #pragma unroll
    for(int i=0;i<4;i++)
      #pragma unroll
      for(int j=0;j<4;j++)
        acc[i][j] = __builtin_amdgcn_mfma_f32_16x16x32_bf16(af[i], bfv[j], acc[i][j], 0, 0, 0);
  }

  float alpha = 0.f;
  if(EPI==2) alpha = log1pf(__expf(araw[blk]));

  #pragma unroll
  for(int i=0;i<4;i++){
    int row_b = m0 + wm*64 + i*16 + (l>>4)*4;
    #pragma unroll
    for(int j=0;j<4;j++){
      int col = n0 + wn*64 + j*16 + (l&15);
      #pragma unroll
      for(int r=0;r<4;r++){
        int row = row_b + r;
        if(row >= M) continue;
        float v = acc[i][j][r];
        if(EPI==1){
          Cb[(size_t)row*ldc + col] = f2bf(v > 0.f ? v : 0.f);
        } else if(EPI==2){
          Cf[(size_t)row*768 + col] += alpha * v;
        } else if(EPI==3){
          int pb = row / 196, pn = row - pb*196;
          Cf[((size_t)pb*197 + 1 + pn)*768 + col] = v + aux0[col] + aux1[(size_t)(1+pn)*768 + col];
        } else { // EPI==4
          int pb = row / 197, rr3 = row - pb*197;
          if(rr3 > 0) Cf[((size_t)pb*196 + rr3 - 1)*768 + col] = v + aux0[col];
        }
      }
    }
  }
}

// ---------------- LN: mode 0 = EnergyLN (scalar gamma + per-dim bias), 1 = final LN ----------
// vectorized: 192 threads x f32x4 loads (768 = 192*4)
__global__ __launch_bounds__(256)
void norm_k(const float* __restrict__ t, u16* __restrict__ out,
            const float* __restrict__ gv, const float* __restrict__ bv, int blk, int mode)
{
  __shared__ float r1[4], r2[4];
  int row = blockIdx.x;
  const float* tr = t + (size_t)row*768;
  int tid = threadIdx.x, w = tid>>6, l = tid&63;
  f32x4 v = (f32x4){0.f,0.f,0.f,0.f};
  float s=0.f, s2=0.f;
  if(tid < 192){
    v = ((const f32x4*)tr)[tid];
    s  = v[0]+v[1]+v[2]+v[3];
    s2 = v[0]*v[0]+v[1]*v[1]+v[2]*v[2]+v[3]*v[3];
  }
  s = wred_sum(s); s2 = wred_sum(s2);
  if(l==0){ r1[w]=s; r2[w]=s2; }
  __syncthreads();
  s  = r1[0]+r1[1]+r1[2]+r1[3];
  s2 = r2[0]+r2[1]+r2[2]+r2[3];
  float mu  = s * (1.0f/768.0f);
  float var = s2 * (1.0f/768.0f) - mu*mu;
  float rs  = rsqrtf(var + LN_EPS);
  u16* orow = out + (size_t)row*768;
  if(tid < 192){
    short4v o;
    if(mode==0){
      float gm = gv[blk];
      const float* bb = bv + blk*768;
      #pragma unroll
      for(int c=0;c<4;c++) o[c] = (short)f2bf((v[c]-mu)*rs*gm + bb[tid*4+c]);
    } else {
      #pragma unroll
      for(int c=0;c<4;c++) o[c] = (short)f2bf((v[c]-mu)*rs*gv[tid*4+c] + bv[tid*4+c]);
    }
    ((short4v*)orow)[tid] = o;
  }
}

// ---------------- fused QK-projection + attention per (b,h), 8 waves --------------------------
// Grid 768 x 512 threads, __launch_bounds__(512,2). 8 waves = 2/SIMD is the sweet spot (R7:
// 16 waves regressed -- barrier-serialized kernel). Phase A staging is R6's row-major slab
// (R8's chunk-major de-coalesced the GLOBAL staging reads: consecutive lanes hit consecutive
// rows 1536B apart = 64 lines/wave; row-major groups 4 lanes per 64B line).
// Phase B: 2 barriers per stripe (top barrier removed -- the SredS barrier of stripe st already
// orders st's P/PT writes after st-1's Gq/Gk reads, and the post-P barrier orders st+1's SredS
// writes after st's SredS reads).
__global__ __launch_bounds__(512, 2)
void attn_fused(const u16* __restrict__ g, const u16* __restrict__ Wqk,
                u16* __restrict__ GqO, u16* __restrict__ GkO)
{
  __shared__ u16 smem[76800];          // 153,600 B
  __shared__ float SredS[2][4][16];
  u16* Qlds = smem;                    // [208][72]  29,952 B
  u16* Klds = smem + 14976;            // [208][72]
  u16* QTl  = smem + 29952;            // [64][232]  29,696 B
  u16* KTl  = smem + 44800;            // [64][232]
  u16* P    = smem + 59648;            // [32][256]  16,384 B (phase B)
  u16* PT   = smem + 67840;            // [224][40]  17,920 B (phase B)
  u16* lg   = smem + 59648;            // phase-A alias: [2][832*8] = 26,624 B <= P+PT region

  int bhw = blockIdx.x;
  int bh = (bhw & 7)*96 + (bhw >> 3);   // bijective XCD chunk swizzle (768 % 8 == 0)
  int b = bh/12, h = bh - b*12;
  const u16* grows = g + (size_t)b*197*768;
  u16* Qg = GqO + (size_t)b*197*768 + h*64;
  u16* Kg = GkO + (size_t)b*197*768 + h*64;
  int tid = threadIdx.x, w = tid>>6, l = tid&63;
  int lane16 = l & 15, quad = l >> 4;

  // zero transposed-pad cols 208..231 (read by Gq kt=6 / Gk st=6 upper quads)
  for(int idx=tid; idx<64*24; idx+=512){
    int z = idx/24, c = 208 + (idx - (idx/24)*24);
    QTl[z*232 + c] = 0; KTl[z*232 + c] = 0;
  }

  // ---- phase A: projection, staged (R6 row-major slab [208 rows][32 cols]) ----
  {
    int half = w >> 2;                   // 0=Q, 1=K
    int wsub = w & 3;                    // rt row-group
    int rt0 = (wsub==0) ? 0 : 1 + 3*wsub;
    int rtn = (wsub==0) ? 4 : 3;
    const u16* Wb = Wqk + (size_t)half*589824 + (size_t)(h*64)*768;
    u16* Lr = half ? Klds : Qlds;
    u16* Lt = half ? KTl  : QTl;
    f32x4 acc[4][4];
    #pragma unroll
    for(int i=0;i<4;i++)
      #pragma unroll
      for(int z=0;z<4;z++) acc[i][z] = (f32x4){0.f,0.f,0.f,0.f};

    // slab staging: 208 rows x 32 cols bf16 = 832 16B-chunks; chunk idx -> (row=idx>>2, c4=idx&3)
    #define STAGE_G(bufi, ktv) do{                                                    \
      { int rw = tid>>2, c4 = tid&3; int r2 = rw>196?196:rw;                          \
        async16(grows + (size_t)r2*768 + (ktv)*32 + c4*8, lg + (bufi)*6656 + tid*8);} \
      int i1 = tid + 512;                                                             \
      if(i1 < 832){ int rw = i1>>2, c4 = i1&3; int r2 = rw>196?196:rw;                \
        async16(grows + (size_t)r2*768 + (ktv)*32 + c4*8, lg + (bufi)*6656 + i1*8);}  \
    }while(0)

    short8 bq[4], bqn[4];
    #pragma unroll
    for(int z=0;z<4;z++) bq[z] = *(const short8*)(Wb + (size_t)(z*16+lane16)*768 + quad*8);
    STAGE_G(0, 0);
    int buf = 0;
    for(int kt=0; kt<24; kt++){
      __syncthreads();                  // drains vmcnt -> slab[buf] ready
      if(kt < 23){
        STAGE_G(buf^1, kt+1);
        #pragma unroll
        for(int z=0;z<4;z++)
          bqn[z] = *(const short8*)(Wb + (size_t)(z*16+lane16)*768 + (kt+1)*32 + quad*8);
      }
      const u16* lb = lg + buf*6656;
      #pragma unroll
      for(int i=0;i<4;i++) if(i<rtn){
        short8 af = *(const short8*)(lb + (size_t)((rt0+i)*16 + lane16)*32 + quad*8);
        #pragma unroll
        for(int z=0;z<4;z++)
          acc[i][z] = __builtin_amdgcn_mfma_f32_16x16x32_bf16(af, bq[z], acc[i][z],0,0,0);
      }
      #pragma unroll
      for(int z=0;z<4;z++) bq[z] = bqn[z];
      buf ^= 1;
    }
    #undef STAGE_G

    #pragma unroll
    for(int i=0;i<4;i++) if(i<rtn)
      #pragma unroll
      for(int z=0;z<4;z++)
        #pragma unroll
        for(int r=0;r<4;r++){
          int q  = (rt0+i)*16 + quad*4 + r;   // D-layout: row=(l>>4)*4+r
          int zz = z*16 + lane16;             //           col=l&15
          u16 hv = f2bf(acc[i][z][r]);
          Lr[q*72   + zz] = hv;
          Lt[zz*232 + q ] = hv;
        }
  }
  __syncthreads();

  // zero P logical cols 208..223 once (never overwritten: P data writes have j<208; separated
  // from the first Gq read by the st=0 SredS + post-P barriers).
  {
    int q = tid>>4, j = 208 + (tid&15);
    P[q*256 + 8*((j>>3)^(q&7)) + (j&7)] = 0;
  }

  // ---- phase B: attention body, LDS-sourced, 8-wave split, 2 barriers/stripe
  int mt = w & 1, nh = w >> 1;                  // mt: q-half of stripe; nh: 0..3
  int ncnt = (nh==0) ? 4 : 3;                   // score n-tiles: {4,3,3,3} over 13
  int nt0s = (nh==0) ? 0 : (1 + 3*nh);
  int jt0 = (w<5) ? 2*w : 10+(w-5);             // Gk j-tiles: {2,2,2,2,2,1,1,1}
  int jn  = (w<5) ? 2 : 1;

  f32x4 gk[2][4];
  #pragma unroll
  for(int a=0;a<2;a++)
    #pragma unroll
    for(int n2=0;n2<4;n2++) gk[a][n2] = (f32x4){0.f,0.f,0.f,0.f};

  for(int st=0; st<7; st++){
    int q0 = st*32;
    // (no top barrier: SredS barrier below orders our P/PT writes after ALL waves' previous
    //  Gq/Gk reads; post-P barrier orders next stripe's SredS writes after this stripe's reads)
    int qa = q0 + 16*mt + lane16; if(qa > 196) qa = 196;
    short8 a0 = *(const short8*)&Qlds[qa*72 + quad*8];
    short8 a1 = *(const short8*)&Qlds[qa*72 + 32 + quad*8];
    f32x4 sa[4];
    #pragma unroll
    for(int ni=0;ni<4;ni++) sa[ni] = (f32x4){0.f,0.f,0.f,0.f};
    for(int ni=0; ni<ncnt; ni++){
      int jb = (nt0s+ni)*16 + lane16; if(jb > 196) jb = 196;
      short8 b0 = *(const short8*)&Klds[jb*72 + quad*8];
      short8 b1 = *(const short8*)&Klds[jb*72 + 32 + quad*8];
      sa[ni] = __builtin_amdgcn_mfma_f32_16x16x32_bf16(a0, b0, sa[ni],0,0,0);
      sa[ni] = __builtin_amdgcn_mfma_f32_16x16x32_bf16(a1, b1, sa[ni],0,0,0);
    }
    for(int ni=0; ni<ncnt; ni++){
      if((nt0s+ni)*16 + lane16 > 196){
        sa[ni][0]=-3e38f; sa[ni][1]=-3e38f; sa[ni][2]=-3e38f; sa[ni][3]=-3e38f;
      }
    }
    // no-max softmax (beta=0.125, logits bounded; arg clamped)
    float ss[4] = {0.f,0.f,0.f,0.f};
    for(int ni=0; ni<ncnt; ni++)
      #pragma unroll
      for(int r=0;r<4;r++){
        float e = __expf(fminf(ATT_BETA*sa[ni][r], 80.f));
        sa[ni][r] = e; ss[r] += e;
      }
    #pragma unroll
    for(int o=1;o<16;o<<=1)
      #pragma unroll
      for(int r=0;r<4;r++) ss[r] += __shfl_xor(ss[r], o, 64);
    if(lane16==0){
      #pragma unroll
      for(int r=0;r<4;r++) SredS[mt][nh][quad*4+r] = ss[r];
    }
    __syncthreads();
    float inv[4];
    #pragma unroll
    for(int r=0;r<4;r++)
      inv[r] = 1.f/(SredS[mt][0][quad*4+r] + SredS[mt][1][quad*4+r]
                  + SredS[mt][2][quad*4+r] + SredS[mt][3][quad*4+r]);
    // write P (swizzled) + PT (packed b64); rows q>196 forced 0
    for(int ni=0; ni<ncnt; ni++){
      int j = (nt0s+ni)*16 + lane16;
      short4v pk;
      #pragma unroll
      for(int r=0;r<4;r++){
        int q = 16*mt + quad*4 + r;
        float val = (q0 + q <= 196) ? sa[ni][r]*inv[r] : 0.f;
        u16 hv = f2bf(val);
        P[q*256 + 8*((j>>3)^(q&7)) + (j&7)] = hv;
        pk[r] = (short)hv;
      }
      *(short4v*)&PT[j*40 + 16*mt + 4*quad] = pk;
    }
    __syncthreads();
    // ---- Gq = P K : one 16x16 tile per wave (mt x nh), B-frags from KTl
    {
      f32x4 gq = (f32x4){0.f,0.f,0.f,0.f};
      int qrow = 16*mt + lane16;
      int z = nh*16 + lane16;
      for(int kt=0; kt<7; kt++){
        short8 af = *(const short8*)&P[qrow*256 + 8*((4*kt+quad)^(qrow&7))];
        short8 bf8 = *(const short8*)&KTl[z*232 + kt*32 + quad*8];
        gq = __builtin_amdgcn_mfma_f32_16x16x32_bf16(af, bf8, gq,0,0,0);
      }
      #pragma unroll
      for(int r=0;r<4;r++){
        int qg2 = q0 + 16*mt + quad*4 + r;
        if(qg2 <= 196) Qg[(size_t)qg2*768 + nh*16 + lane16] = f2bf(gq[r]);
      }
    }
    // ---- Gk accumulate: A-frags from PT, B-frags from QTl
    {
      short8 bq2[4];
      #pragma unroll
      for(int n2=0;n2<4;n2++)
        bq2[n2] = *(const short8*)&QTl[(n2*16+lane16)*232 + q0 + quad*8];
      for(int ji=0; ji<jn; ji++){
        int j = (jt0+ji)*16 + lane16;
        short8 af = *(const short8*)&PT[j*40 + quad*8];
        #pragma unroll
        for(int n2=0;n2<4;n2++)
          gk[ji][n2] = __builtin_amdgcn_mfma_f32_16x16x32_bf16(af, bq2[n2], gk[ji][n2],0,0,0);
      }
    }
  }
  __syncthreads();
  for(int ji=0; ji<jn; ji++){
    int jt = jt0 + ji;
    #pragma unroll
    for(int n2=0;n2<4;n2++)
      #pragma unroll
      for(int r=0;r<4;r++){
        int j = jt*16 + quad*4 + r;
        if(j <= 196) Kg[(size_t)j*768 + n2*16 + lane16] = f2bf(gk[ji][n2][r]);
      }
  }
}

// ---------------- small utility kernels ----------------
__global__ void cvt_k(const float* __restrict__ in, u16* __restrict__ out, int n){
  for(int i=blockIdx.x*256+threadIdx.x; i<n; i+=gridDim.x*256) out[i] = f2bf(in[i]);
}

// dst[c*dstride + coff + r] = bf16(src[r*C + c]); R,C multiples of 32
__global__ __launch_bounds__(256)
void tr_k(const float* __restrict__ src, u16* __restrict__ dst, int R, int C, int dstride, int coff){
  __shared__ float tile[32][33];
  int c0 = blockIdx.x*32, r0 = blockIdx.y*32;
  int tx = threadIdx.x & 31, ty = threadIdx.x >> 5;
  for(int i=ty;i<32;i+=8) tile[i][tx] = src[(size_t)(r0+i)*C + c0 + tx];
  __syncthreads();
  for(int i=ty;i<32;i+=8) dst[(size_t)(c0+i)*dstride + coff + r0 + tx] = f2bf(tile[tx][i]);
}

__global__ void fill_cls_k(float* __restrict__ t, const float* __restrict__ cls, const float* __restrict__ pos){
  int b = blockIdx.x;
  for(int i=threadIdx.x;i<768;i+=256) t[(size_t)b*197*768 + i] = cls[i] + pos[i];
}

// ---------------- launch ----------------
extern "C" void kernel_launch(void* const* d_in, const int* in_sizes, int n_in,
                              void* d_out, int out_size, void* d_ws, size_t ws_size,
                              hipStream_t stream){
  const float* x      = (const float*)d_in[0];
  const float* W_enc  = (const float*)d_in[1];
  const float* b_enc  = (const float*)d_in[2];
  const float* cls    = (const float*)d_in[3];
  const float* pos    = (const float*)d_in[4];
  const float* gamma  = (const float*)d_in[5];
  const float* bias   = (const float*)d_in[6];
  const float* Wq     = (const float*)d_in[7];
  const float* Wk     = (const float*)d_in[8];
  const float* Whn    = (const float*)d_in[9];
  const float* araw   = (const float*)d_in[10];
  const float* ln_g   = (const float*)d_in[11];
  const float* ln_b   = (const float*)d_in[12];
  const float* W_dec  = (const float*)d_in[13];
  const float* b_dec  = (const float*)d_in[14];
  float* out = (float*)d_out;
  (void)in_sizes; (void)n_in; (void)out_size;

  const int M  = 64*197;   // 12608
  const int MX = 64*196;   // 12544

  // ---- workspace ----
  char* p = (char*)d_ws;
  float* t   = (float*)p;  p += (size_t)M*768*4;        // 38.7 MB
  u16*   g   = (u16*)p;    p += (size_t)M*768*2;        // 19.4 MB (LN out)
  u16*   Qb  = (u16*)p;    p += (size_t)M*768*2;        // 19.4 MB (Gq out; xb overlay)
  u16*   Kb  = (u16*)p;    p += (size_t)M*768*2;        // 19.4 MB (Gk out; WencT/WdecT overlay)
  size_t base = (size_t)(p - (char*)d_ws);
  if(base > ws_size) return;
  // merged-hopfield hidden buffer (77.46 MB) if it fits, else 2-chunk overlay on Qb/Kb
  u16* hidden; int hop_merged;
  if(base + (size_t)M*3072*2 <= ws_size){ hidden = (u16*)(d_ws) + base/2; hop_merged = 1; }
  else { hidden = Qb; hop_merged = 0; }

  // ---- weights live inside d_out (28.3 MB of 38.5 MB; fully dead before decode write) ----
  u16* Wall = (u16*)d_out;
  u16* Wqkb = Wall;               // 2 x [Wq(768 rows); Wk(768 rows)] x 768
  u16* WqkT = Wall + 2359296;     // 2 x 768 x [WqT | WkT] (stride 1536)
  u16* WhnT = Wall + 4718592;     // 2 x 3072 x 768
  u16* WhnB = Wall + 9437184;     // 2 x 768 x 3072 (row-major, ldb 3072)
  u16* xb    = Qb;                // encode-time overlay
  u16* WencT = Kb;                // encode-time overlay
  u16* WdecT = Kb;                // decode-time overlay

  // ---- weight prep ----
  for(int b=0;b<2;b++){
    cvt_k<<<512,256,0,stream>>>(Wq + (size_t)b*589824, Wqkb + (size_t)b*1179648, 589824);
    cvt_k<<<512,256,0,stream>>>(Wk + (size_t)b*589824, Wqkb + (size_t)b*1179648 + 589824, 589824);
    tr_k<<<dim3(24,24),256,0,stream>>>(Wq + (size_t)b*589824, WqkT + (size_t)b*1179648, 768,768, 1536, 0);
    tr_k<<<dim3(24,24),256,0,stream>>>(Wk + (size_t)b*589824, WqkT + (size_t)b*1179648, 768,768, 1536, 768);
    tr_k<<<dim3(96,24),256,0,stream>>>(Whn + (size_t)b*2359296, WhnT + (size_t)b*2359296, 768,3072, 768, 0);
    cvt_k<<<2048,256,0,stream>>>(Whn + (size_t)b*2359296, WhnB + (size_t)b*2359296, 2359296);
  }

  // ---- encode: t = [cls; x@W_enc + b_enc] + pos ----
  cvt_k<<<1024,256,0,stream>>>(x, xb, MX*768);
  tr_k<<<dim3(24,24),256,0,stream>>>(W_enc, WencT, 768,768, 768, 0);
  fill_cls_k<<<64,256,0,stream>>>(t, cls, pos);
  gemm_bt<3,0><<<dim3(6,98),256,0,stream>>>(xb, nullptr, WencT, nullptr, t,
                                            MX, 768, 768, 768, 768,
                                            b_enc, pos, nullptr, 0);

  // ---- energy-descent blocks ----
  for(int blk=0; blk<2; blk++){
    for(int s=0; s<4; s++){
      norm_k<<<M,256,0,stream>>>(t, g, gamma, bias, blk, 0);
      if(hop_merged){
        gemm_bt<1,0><<<dim3(24,99),256,0,stream>>>(g, nullptr,
            WhnT + (size_t)blk*2359296,
            hidden, nullptr, M, 3072, 768, 768, 3072,
            nullptr, nullptr, nullptr, 0);
        gemm_bt<2,0><<<dim3(6,99),256,0,stream>>>(hidden, nullptr,
            WhnB + (size_t)blk*2359296,
            nullptr, t, M, 768, 3072, 3072, 768,
            nullptr, nullptr, araw, blk);
      } else {
        for(int c=0;c<2;c++){
          gemm_bt<1,0><<<dim3(12,99),256,0,stream>>>(g, nullptr,
              WhnT + (size_t)blk*2359296 + (size_t)c*1536*768,
              hidden, nullptr, M, 1536, 768, 768, 1536,
              nullptr, nullptr, nullptr, 0);
          gemm_bt<2,0><<<dim3(6,99),256,0,stream>>>(hidden, nullptr,
              WhnB + (size_t)blk*2359296 + (size_t)c*1536,
              nullptr, t, M, 768, 1536, 3072, 768,
              nullptr, nullptr, araw, blk);
        }
      }
      // fused QK-projection + attention: reads g + Wqk, writes Gq -> Qb, Gk -> Kb
      attn_fused<<<768,512,0,stream>>>(g, Wqkb + (size_t)blk*1179648, Qb, Kb);
      // gradient projection (merged K=1536, split-A: A=Gq(Qb), A2=Gk(Kb))
      gemm_bt<2,1><<<dim3(6,99),256,0,stream>>>(Qb, Kb, WqkT + (size_t)blk*1179648,
            nullptr, t, M, 768, 1536, 1536, 768,
            nullptr, nullptr, araw, blk);
    }
  }

  // ---- decode: LN -> GEMM -> drop CLS ----
  tr_k<<<dim3(24,24),256,0,stream>>>(W_dec, WdecT, 768,768, 768, 0);
  norm_k<<<M,256,0,stream>>>(t, g, ln_g, ln_b, 0, 1);
  gemm_bt<4,0><<<dim3(6,99),256,0,stream>>>(g, nullptr, WdecT, nullptr, out,
                                            M, 768, 768, 768, 768,
                                            b_dec, nullptr, nullptr, 0);
}

// Round 10
// 3809.488 us; speedup vs baseline: 1.3104x; 1.0581x over previous
//
#include <hip/hip_runtime.h>
#include <cstdint>
#include <cstddef>

using u16 = unsigned short;
typedef short short8 __attribute__((ext_vector_type(8)));
typedef short short4v __attribute__((ext_vector_type(4)));
typedef float f32x4 __attribute__((ext_vector_type(4)));

#define LN_EPS 1e-5f
#define ATT_BETA 0.125f

__device__ __forceinline__ u16 f2bf(float f){
  uint32_t u = __float_as_uint(f);
  u += 0x7fffu + ((u >> 16) & 1u);
  return (u16)(u >> 16);
}
__device__ __forceinline__ float bf2f(u16 h){
  return __uint_as_float(((uint32_t)h) << 16);
}
__device__ __forceinline__ float wred_sum(float v){
  #pragma unroll
  for(int o=32;o;o>>=1) v += __shfl_xor(v,o,64);
  return v;
}
__device__ __forceinline__ void async16(const void* g, void* l){
  __builtin_amdgcn_global_load_lds((const __attribute__((address_space(1))) void*)g,
                                   (__attribute__((address_space(3))) void*)l, 16, 0, 0);
}

// ---------------- generic bf16 MFMA GEMM: C[M,N] = A[M,K] * B[N,K]^T (B row stride ldb) -------
// EPI: 1=bf16+relu out (row stride ldc), 2=t += alpha*acc (plain RMW), 3=encode epilogue,
//      4=decode epilogue
// ASPL: A operand split: k<768 from A, k>=768 from A2 (both row stride 768)
// Block-id XCD swizzle (bijective, m204): round-robin dispatch -> contiguous per-XCD chunks.
// K-loop: stage-ahead double-buffered (T3 minimum 2-phase): STAGE(next) issued BEFORE compute,
// ONE __syncthreads per kt whose implicit vmcnt(0) drain waits exactly the next tile's loads
// (which had the whole MFMA phase in flight). Replaces the old barrier-STAGE-drain-compute
// (2 barriers + full serial load latency per kt).
template<int EPI, int ASPL>
__global__ __launch_bounds__(256)
void gemm_bt(const u16* __restrict__ A, const u16* __restrict__ A2,
             const u16* __restrict__ B,
             u16* __restrict__ Cb, float* __restrict__ Cf,
             int M, int N, int K, int ldb, int ldc,
             const float* __restrict__ aux0, const float* __restrict__ aux1,
             const float* __restrict__ araw, int blk)
{
  __shared__ u16 lA[2][128*32];
  __shared__ u16 lB[2][128*32];
  int tid = threadIdx.x;
  int w = tid >> 6, l = tid & 63;
  int wm = w >> 1, wn = w & 1;
  unsigned nwg = gridDim.x*gridDim.y;
  unsigned lin = blockIdx.y*gridDim.x + blockIdx.x;
  unsigned qq = nwg>>3, rr = nwg&7, xcd = lin&7, idx = lin>>3;
  unsigned swz = (xcd<rr ? xcd*(qq+1) : rr*(qq+1) + (xcd-rr)*qq) + idx;
  int m0 = (int)(swz / gridDim.x) * 128, n0 = (int)(swz % gridDim.x) * 128;
  int lr = l >> 2;           // row within 16-row chunk
  int lc = (l & 3) * 8;      // col (elements) within 32-wide K slab
  f32x4 acc[4][4];
  #pragma unroll
  for(int i=0;i<4;i++)
    #pragma unroll
    for(int j=0;j<4;j++) acc[i][j] = (f32x4){0.f,0.f,0.f,0.f};
  int fm = l & 15, fq = (l >> 4) * 8;

  #define STAGE_AB(bufi, ktv) do{                                            \
    const u16* Asrc = A; int kcol = (ktv);                                   \
    if(ASPL){ if((ktv) >= 768){ Asrc = A2; kcol = (ktv) - 768; } }           \
    int lda = ASPL ? 768 : K;                                                \
    _Pragma("unroll")                                                        \
    for(int c=0;c<2;c++){                                                    \
      int rr2 = (w*2+c)*16;                                                  \
      int ga = m0 + rr2 + lr; if(ga > M-1) ga = M-1;                         \
      async16(Asrc + (size_t)ga*lda + kcol + lc, &lA[bufi][rr2*32]);         \
      int gb = n0 + rr2 + lr; if(gb > N-1) gb = N-1;                         \
      async16(B + (size_t)gb*ldb + (ktv) + lc, &lB[bufi][rr2*32]);           \
    }                                                                        \
  }while(0)

  STAGE_AB(0, 0);
  __syncthreads();                      // slab 0 ready (vmcnt(0)+barrier)
  int buf = 0;
  for(int kt=0; kt<K; kt+=32){
    if(kt+32 < K) STAGE_AB(buf^1, kt+32);   // next tile in flight during MFMA below
    short8 af[4], bfv[4];
    #pragma unroll
    for(int i=0;i<4;i++) af[i]  = *(const short8*)&lA[buf][(wm*64 + i*16 + fm)*32 + fq];
    #pragma unroll
    for(int j=0;j<4;j++) bfv[j] = *(const short8*)&lB[buf][(wn*64 + j*16 + fm)*32 + fq];
    #pragma unroll
    for(int i=0;i<4;i++)
      #pragma unroll
      for(int j=0;j<4;j++)
        acc[i][j] = __builtin_amdgcn_mfma_f32_16x16x32_bf16(af[i], bfv[j], acc[i][j], 0, 0, 0);
    __syncthreads();                    // drains next tile's loads + our ds_reads; 1 barrier/kt
    buf ^= 1;
  }
  #undef STAGE_AB

  float alpha = 0.f;
  if(EPI==2) alpha = log1pf(__expf(araw[blk]));

  #pragma unroll
  for(int i=0;i<4;i++){
    int row_b = m0 + wm*64 + i*16 + (l>>4)*4;
    #pragma unroll
    for(int j=0;j<4;j++){
      int col = n0 + wn*64 + j*16 + (l&15);
      #pragma unroll
      for(int r=0;r<4;r++){
        int row = row_b + r;
        if(row >= M) continue;
        float v = acc[i][j][r];
        if(EPI==1){
          Cb[(size_t)row*ldc + col] = f2bf(v > 0.f ? v : 0.f);
        } else if(EPI==2){
          Cf[(size_t)row*768 + col] += alpha * v;
        } else if(EPI==3){
          int pb = row / 196, pn = row - pb*196;
          Cf[((size_t)pb*197 + 1 + pn)*768 + col] = v + aux0[col] + aux1[(size_t)(1+pn)*768 + col];
        } else { // EPI==4
          int pb = row / 197, rr3 = row - pb*197;
          if(rr3 > 0) Cf[((size_t)pb*196 + rr3 - 1)*768 + col] = v + aux0[col];
        }
      }
    }
  }
}

// ---------------- LN: mode 0 = EnergyLN (scalar gamma + per-dim bias), 1 = final LN ----------
// vectorized: 192 threads x f32x4 loads (768 = 192*4)
__global__ __launch_bounds__(256)
void norm_k(const float* __restrict__ t, u16* __restrict__ out,
            const float* __restrict__ gv, const float* __restrict__ bv, int blk, int mode)
{
  __shared__ float r1[4], r2[4];
  int row = blockIdx.x;
  const float* tr = t + (size_t)row*768;
  int tid = threadIdx.x, w = tid>>6, l = tid&63;
  f32x4 v = (f32x4){0.f,0.f,0.f,0.f};
  float s=0.f, s2=0.f;
  if(tid < 192){
    v = ((const f32x4*)tr)[tid];
    s  = v[0]+v[1]+v[2]+v[3];
    s2 = v[0]*v[0]+v[1]*v[1]+v[2]*v[2]+v[3]*v[3];
  }
  s = wred_sum(s); s2 = wred_sum(s2);
  if(l==0){ r1[w]=s; r2[w]=s2; }
  __syncthreads();
  s  = r1[0]+r1[1]+r1[2]+r1[3];
  s2 = r2[0]+r2[1]+r2[2]+r2[3];
  float mu  = s * (1.0f/768.0f);
  float var = s2 * (1.0f/768.0f) - mu*mu;
  float rs  = rsqrtf(var + LN_EPS);
  u16* orow = out + (size_t)row*768;
  if(tid < 192){
    short4v o;
    if(mode==0){
      float gm = gv[blk];
      const float* bb = bv + blk*768;
      #pragma unroll
      for(int c=0;c<4;c++) o[c] = (short)f2bf((v[c]-mu)*rs*gm + bb[tid*4+c]);
    } else {
      #pragma unroll
      for(int c=0;c<4;c++) o[c] = (short)f2bf((v[c]-mu)*rs*gv[tid*4+c] + bv[tid*4+c]);
    }
    ((short4v*)orow)[tid] = o;
  }
}

// ---------------- fused QK-projection + attention per (b,h), 8 waves --------------------------
// Grid 768 x 512 threads, __launch_bounds__(512,2). 8 waves = 2/SIMD (R7: 16 waves regressed).
// Phase A: R6 row-major slab staging (stage-ahead, 1 barrier/kt). Phase B: R6-exact 3-barrier
// stripe loop (R9 removed the top barrier: -14us regression -- barrier keeps waves converged
// so LDS streams don't interleave destructively; reverted).
__global__ __launch_bounds__(512, 2)
void attn_fused(const u16* __restrict__ g, const u16* __restrict__ Wqk,
                u16* __restrict__ GqO, u16* __restrict__ GkO)
{
  __shared__ u16 smem[76800];          // 153,600 B
  __shared__ float SredS[2][4][16];
  u16* Qlds = smem;                    // [208][72]  29,952 B
  u16* Klds = smem + 14976;            // [208][72]
  u16* QTl  = smem + 29952;            // [64][232]  29,696 B
  u16* KTl  = smem + 44800;            // [64][232]
  u16* P    = smem + 59648;            // [32][256]  16,384 B (phase B)
  u16* PT   = smem + 67840;            // [224][40]  17,920 B (phase B)
  u16* lg   = smem + 59648;            // phase-A alias: [2][832*8] = 26,624 B <= P+PT region

  int bhw = blockIdx.x;
  int bh = (bhw & 7)*96 + (bhw >> 3);   // bijective XCD chunk swizzle (768 % 8 == 0)
  int b = bh/12, h = bh - b*12;
  const u16* grows = g + (size_t)b*197*768;
  u16* Qg = GqO + (size_t)b*197*768 + h*64;
  u16* Kg = GkO + (size_t)b*197*768 + h*64;
  int tid = threadIdx.x, w = tid>>6, l = tid&63;
  int lane16 = l & 15, quad = l >> 4;

  // zero transposed-pad cols 208..231 (read by Gq kt=6 / Gk st=6 upper quads)
  for(int idx=tid; idx<64*24; idx+=512){
    int z = idx/24, c = 208 + (idx - (idx/24)*24);
    QTl[z*232 + c] = 0; KTl[z*232 + c] = 0;
  }

  // ---- phase A: projection, staged (row-major slab [208 rows][32 cols]) ----
  {
    int half = w >> 2;                   // 0=Q, 1=K
    int wsub = w & 3;                    // rt row-group
    int rt0 = (wsub==0) ? 0 : 1 + 3*wsub;
    int rtn = (wsub==0) ? 4 : 3;
    const u16* Wb = Wqk + (size_t)half*589824 + (size_t)(h*64)*768;
    u16* Lr = half ? Klds : Qlds;
    u16* Lt = half ? KTl  : QTl;
    f32x4 acc[4][4];
    #pragma unroll
    for(int i=0;i<4;i++)
      #pragma unroll
      for(int z=0;z<4;z++) acc[i][z] = (f32x4){0.f,0.f,0.f,0.f};

    // slab staging: 208 rows x 32 cols bf16 = 832 16B-chunks; chunk idx -> (row=idx>>2, c4=idx&3)
    #define STAGE_G(bufi, ktv) do{                                                    \
      { int rw = tid>>2, c4 = tid&3; int r2 = rw>196?196:rw;                          \
        async16(grows + (size_t)r2*768 + (ktv)*32 + c4*8, lg + (bufi)*6656 + tid*8);} \
      int i1 = tid + 512;                                                             \
      if(i1 < 832){ int rw = i1>>2, c4 = i1&3; int r2 = rw>196?196:rw;                \
        async16(grows + (size_t)r2*768 + (ktv)*32 + c4*8, lg + (bufi)*6656 + i1*8);}  \
    }while(0)

    short8 bq[4], bqn[4];
    #pragma unroll
    for(int z=0;z<4;z++) bq[z] = *(const short8*)(Wb + (size_t)(z*16+lane16)*768 + quad*8);
    STAGE_G(0, 0);
    int buf = 0;
    for(int kt=0; kt<24; kt++){
      __syncthreads();                  // drains vmcnt -> slab[buf] ready
      if(kt < 23){
        STAGE_G(buf^1, kt+1);
        #pragma unroll
        for(int z=0;z<4;z++)
          bqn[z] = *(const short8*)(Wb + (size_t)(z*16+lane16)*768 + (kt+1)*32 + quad*8);
      }
      const u16* lb = lg + buf*6656;
      #pragma unroll
      for(int i=0;i<4;i++) if(i<rtn){
        short8 af = *(const short8*)(lb + (size_t)((rt0+i)*16 + lane16)*32 + quad*8);
        #pragma unroll
        for(int z=0;z<4;z++)
          acc[i][z] = __builtin_amdgcn_mfma_f32_16x16x32_bf16(af, bq[z], acc[i][z],0,0,0);
      }
      #pragma unroll
      for(int z=0;z<4;z++) bq[z] = bqn[z];
      buf ^= 1;
    }
    #undef STAGE_G

    #pragma unroll
    for(int i=0;i<4;i++) if(i<rtn)
      #pragma unroll
      for(int z=0;z<4;z++)
        #pragma unroll
        for(int r=0;r<4;r++){
          int q  = (rt0+i)*16 + quad*4 + r;   // D-layout: row=(l>>4)*4+r
          int zz = z*16 + lane16;             //           col=l&15
          u16 hv = f2bf(acc[i][z][r]);
          Lr[q*72   + zz] = hv;
          Lt[zz*232 + q ] = hv;
        }
  }
  __syncthreads();

  // ---- phase B: attention body, LDS-sourced, 8-wave split (R6-exact, 3 barriers/stripe)
  int mt = w & 1, nh = w >> 1;                  // mt: q-half of stripe; nh: 0..3
  int ncnt = (nh==0) ? 4 : 3;                   // score n-tiles: {4,3,3,3} over 13
  int nt0s = (nh==0) ? 0 : (1 + 3*nh);
  int jt0 = (w<5) ? 2*w : 10+(w-5);             // Gk j-tiles: {2,2,2,2,2,1,1,1}
  int jn  = (w<5) ? 2 : 1;

  f32x4 gk[2][4];
  #pragma unroll
  for(int a=0;a<2;a++)
    #pragma unroll
    for(int n2=0;n2<4;n2++) gk[a][n2] = (f32x4){0.f,0.f,0.f,0.f};

  for(int st=0; st<7; st++){
    int q0 = st*32;
    __syncthreads();   // protect P/PT/SredS rewrite vs previous stripe readers
    int qa = q0 + 16*mt + lane16; if(qa > 196) qa = 196;
    short8 a0 = *(const short8*)&Qlds[qa*72 + quad*8];
    short8 a1 = *(const short8*)&Qlds[qa*72 + 32 + quad*8];
    f32x4 sa[4];
    #pragma unroll
    for(int ni=0;ni<4;ni++) sa[ni] = (f32x4){0.f,0.f,0.f,0.f};
    for(int ni=0; ni<ncnt; ni++){
      int jb = (nt0s+ni)*16 + lane16; if(jb > 196) jb = 196;
      short8 b0 = *(const short8*)&Klds[jb*72 + quad*8];
      short8 b1 = *(const short8*)&Klds[jb*72 + 32 + quad*8];
      sa[ni] = __builtin_amdgcn_mfma_f32_16x16x32_bf16(a0, b0, sa[ni],0,0,0);
      sa[ni] = __builtin_amdgcn_mfma_f32_16x16x32_bf16(a1, b1, sa[ni],0,0,0);
    }
    for(int ni=0; ni<ncnt; ni++){
      if((nt0s+ni)*16 + lane16 > 196){
        sa[ni][0]=-3e38f; sa[ni][1]=-3e38f; sa[ni][2]=-3e38f; sa[ni][3]=-3e38f;
      }
    }
    // no-max softmax (beta=0.125, logits bounded; arg clamped)
    float ss[4] = {0.f,0.f,0.f,0.f};
    for(int ni=0; ni<ncnt; ni++)
      #pragma unroll
      for(int r=0;r<4;r++){
        float e = __expf(fminf(ATT_BETA*sa[ni][r], 80.f));
        sa[ni][r] = e; ss[r] += e;
      }
    #pragma unroll
    for(int o=1;o<16;o<<=1)
      #pragma unroll
      for(int r=0;r<4;r++) ss[r] += __shfl_xor(ss[r], o, 64);
    if(lane16==0){
      #pragma unroll
      for(int r=0;r<4;r++) SredS[mt][nh][quad*4+r] = ss[r];
    }
    __syncthreads();
    float inv[4];
    #pragma unroll
    for(int r=0;r<4;r++)
      inv[r] = 1.f/(SredS[mt][0][quad*4+r] + SredS[mt][1][quad*4+r]
                  + SredS[mt][2][quad*4+r] + SredS[mt][3][quad*4+r]);
    // write P (swizzled) + PT (packed b64); rows q>196 forced 0
    for(int ni=0; ni<ncnt; ni++){
      int j = (nt0s+ni)*16 + lane16;
      short4v pk;
      #pragma unroll
      for(int r=0;r<4;r++){
        int q = 16*mt + quad*4 + r;
        float val = (q0 + q <= 196) ? sa[ni][r]*inv[r] : 0.f;
        u16 hv = f2bf(val);
        P[q*256 + 8*((j>>3)^(q&7)) + (j&7)] = hv;
        pk[r] = (short)hv;
      }
      *(short4v*)&PT[j*40 + 16*mt + 4*quad] = pk;
    }
    // zero P logical cols 208..223 (read by Gq kt=6 upper quads)
    for(int idx=tid; idx<32*16; idx+=512){
      int q = idx>>4, j = 208 + (idx&15);
      P[q*256 + 8*((j>>3)^(q&7)) + (j&7)] = 0;
    }
    __syncthreads();
    // ---- Gq = P K : one 16x16 tile per wave (mt x nh), B-frags from KTl
    {
      f32x4 gq = (f32x4){0.f,0.f,0.f,0.f};
      int qrow = 16*mt + lane16;
      int z = nh*16 + lane16;
      for(int kt=0; kt<7; kt++){
        short8 af = *(const short8*)&P[qrow*256 + 8*((4*kt+quad)^(qrow&7))];
        short8 bf8 = *(const short8*)&KTl[z*232 + kt*32 + quad*8];
        gq = __builtin_amdgcn_mfma_f32_16x16x32_bf16(af, bf8, gq,0,0,0);
      }
      #pragma unroll
      for(int r=0;r<4;r++){
        int qg2 = q0 + 16*mt + quad*4 + r;
        if(qg2 <= 196) Qg[(size_t)qg2*768 + nh*16 + lane16] = f2bf(gq[r]);
      }
    }
    // ---- Gk accumulate: A-frags from PT, B-frags from QTl
    {
      short8 bq2[4];
      #pragma unroll
      for(int n2=0;n2<4;n2++)
        bq2[n2] = *(const short8*)&QTl[(n2*16+lane16)*232 + q0 + quad*8];
      for(int ji=0; ji<jn; ji++){
        int j = (jt0+ji)*16 + lane16;
        short8 af = *(const short8*)&PT[j*40 + quad*8];
        #pragma unroll
        for(int n2=0;n2<4;n2++)
          gk[ji][n2] = __builtin_amdgcn_mfma_f32_16x16x32_bf16(af, bq2[n2], gk[ji][n2],0,0,0);
      }
    }
  }
  __syncthreads();
  for(int ji=0; ji<jn; ji++){
    int jt = jt0 + ji;
    #pragma unroll
    for(int n2=0;n2<4;n2++)
      #pragma unroll
      for(int r=0;r<4;r++){
        int j = jt*16 + quad*4 + r;
        if(j <= 196) Kg[(size_t)j*768 + n2*16 + lane16] = f2bf(gk[ji][n2][r]);
      }
  }
}

// ---------------- small utility kernels ----------------
__global__ void cvt_k(const float* __restrict__ in, u16* __restrict__ out, int n){
  for(int i=blockIdx.x*256+threadIdx.x; i<n; i+=gridDim.x*256) out[i] = f2bf(in[i]);
}

// dst[c*dstride + coff + r] = bf16(src[r*C + c]); R,C multiples of 32
__global__ __launch_bounds__(256)
void tr_k(const float* __restrict__ src, u16* __restrict__ dst, int R, int C, int dstride, int coff){
  __shared__ float tile[32][33];
  int c0 = blockIdx.x*32, r0 = blockIdx.y*32;
  int tx = threadIdx.x & 31, ty = threadIdx.x >> 5;
  for(int i=ty;i<32;i+=8) tile[i][tx] = src[(size_t)(r0+i)*C + c0 + tx];
  __syncthreads();
  for(int i=ty;i<32;i+=8) dst[(size_t)(c0+i)*dstride + coff + r0 + tx] = f2bf(tile[tx][i]);
}

__global__ void fill_cls_k(float* __restrict__ t, const float* __restrict__ cls, const float* __restrict__ pos){
  int b = blockIdx.x;
  for(int i=threadIdx.x;i<768;i+=256) t[(size_t)b*197*768 + i] = cls[i] + pos[i];
}

// ---------------- launch ----------------
extern "C" void kernel_launch(void* const* d_in, const int* in_sizes, int n_in,
                              void* d_out, int out_size, void* d_ws, size_t ws_size,
                              hipStream_t stream){
  const float* x      = (const float*)d_in[0];
  const float* W_enc  = (const float*)d_in[1];
  const float* b_enc  = (const float*)d_in[2];
  const float* cls    = (const float*)d_in[3];
  const float* pos    = (const float*)d_in[4];
  const float* gamma  = (const float*)d_in[5];
  const float* bias   = (const float*)d_in[6];
  const float* Wq     = (const float*)d_in[7];
  const float* Wk     = (const float*)d_in[8];
  const float* Whn    = (const float*)d_in[9];
  const float* araw   = (const float*)d_in[10];
  const float* ln_g   = (const float*)d_in[11];
  const float* ln_b   = (const float*)d_in[12];
  const float* W_dec  = (const float*)d_in[13];
  const float* b_dec  = (const float*)d_in[14];
  float* out = (float*)d_out;
  (void)in_sizes; (void)n_in; (void)out_size;

  const int M  = 64*197;   // 12608
  const int MX = 64*196;   // 12544

  // ---- workspace ----
  char* p = (char*)d_ws;
  float* t   = (float*)p;  p += (size_t)M*768*4;        // 38.7 MB
  u16*   g   = (u16*)p;    p += (size_t)M*768*2;        // 19.4 MB (LN out)
  u16*   Qb  = (u16*)p;    p += (size_t)M*768*2;        // 19.4 MB (Gq out; xb overlay)
  u16*   Kb  = (u16*)p;    p += (size_t)M*768*2;        // 19.4 MB (Gk out; WencT/WdecT overlay)
  size_t base = (size_t)(p - (char*)d_ws);
  if(base > ws_size) return;
  // merged-hopfield hidden buffer (77.46 MB) if it fits, else 2-chunk overlay on Qb/Kb
  u16* hidden; int hop_merged;
  if(base + (size_t)M*3072*2 <= ws_size){ hidden = (u16*)(d_ws) + base/2; hop_merged = 1; }
  else { hidden = Qb; hop_merged = 0; }

  // ---- weights live inside d_out (28.3 MB of 38.5 MB; fully dead before decode write) ----
  u16* Wall = (u16*)d_out;
  u16* Wqkb = Wall;               // 2 x [Wq(768 rows); Wk(768 rows)] x 768
  u16* WqkT = Wall + 2359296;     // 2 x 768 x [WqT | WkT] (stride 1536)
  u16* WhnT = Wall + 4718592;     // 2 x 3072 x 768
  u16* WhnB = Wall + 9437184;     // 2 x 768 x 3072 (row-major, ldb 3072)
  u16* xb    = Qb;                // encode-time overlay
  u16* WencT = Kb;                // encode-time overlay
  u16* WdecT = Kb;                // decode-time overlay

  // ---- weight prep ----
  for(int b=0;b<2;b++){
    cvt_k<<<512,256,0,stream>>>(Wq + (size_t)b*589824, Wqkb + (size_t)b*1179648, 589824);
    cvt_k<<<512,256,0,stream>>>(Wk + (size_t)b*589824, Wqkb + (size_t)b*1179648 + 589824, 589824);
    tr_k<<<dim3(24,24),256,0,stream>>>(Wq + (size_t)b*589824, WqkT + (size_t)b*1179648, 768,768, 1536, 0);
    tr_k<<<dim3(24,24),256,0,stream>>>(Wk + (size_t)b*589824, WqkT + (size_t)b*1179648, 768,768, 1536, 768);
    tr_k<<<dim3(96,24),256,0,stream>>>(Whn + (size_t)b*2359296, WhnT + (size_t)b*2359296, 768,3072, 768, 0);
    cvt_k<<<2048,256,0,stream>>>(Whn + (size_t)b*2359296, WhnB + (size_t)b*2359296, 2359296);
  }

  // ---- encode: t = [cls; x@W_enc + b_enc] + pos ----
  cvt_k<<<1024,256,0,stream>>>(x, xb, MX*768);
  tr_k<<<dim3(24,24),256,0,stream>>>(W_enc, WencT, 768,768, 768, 0);
  fill_cls_k<<<64,256,0,stream>>>(t, cls, pos);
  gemm_bt<3,0><<<dim3(6,98),256,0,stream>>>(xb, nullptr, WencT, nullptr, t,
                                            MX, 768, 768, 768, 768,
                                            b_enc, pos, nullptr, 0);

  // ---- energy-descent blocks ----
  for(int blk=0; blk<2; blk++){
    for(int s=0; s<4; s++){
      norm_k<<<M,256,0,stream>>>(t, g, gamma, bias, blk, 0);
      if(hop_merged){
        gemm_bt<1,0><<<dim3(24,99),256,0,stream>>>(g, nullptr,
            WhnT + (size_t)blk*2359296,
            hidden, nullptr, M, 3072, 768, 768, 3072,
            nullptr, nullptr, nullptr, 0);
        gemm_bt<2,0><<<dim3(6,99),256,0,stream>>>(hidden, nullptr,
            WhnB + (size_t)blk*2359296,
            nullptr, t, M, 768, 3072, 3072, 768,
            nullptr, nullptr, araw, blk);
      } else {
        for(int c=0;c<2;c++){
          gemm_bt<1,0><<<dim3(12,99),256,0,stream>>>(g, nullptr,
              WhnT + (size_t)blk*2359296 + (size_t)c*1536*768,
              hidden, nullptr, M, 1536, 768, 768, 1536,
              nullptr, nullptr, nullptr, 0);
          gemm_bt<2,0><<<dim3(6,99),256,0,stream>>>(hidden, nullptr,
              WhnB + (size_t)blk*2359296 + (size_t)c*1536,
              nullptr, t, M, 768, 1536, 3072, 768,
              nullptr, nullptr, araw, blk);
        }
      }
      // fused QK-projection + attention: reads g + Wqk, writes Gq -> Qb, Gk -> Kb
      attn_fused<<<768,512,0,stream>>>(g, Wqkb + (size_t)blk*1179648, Qb, Kb);
      // gradient projection (merged K=1536, split-A: A=Gq(Qb), A2=Gk(Kb))
      gemm_bt<2,1><<<dim3(6,99),256,0,stream>>>(Qb, Kb, WqkT + (size_t)blk*1179648,
            nullptr, t, M, 768, 1536, 1536, 768,
            nullptr, nullptr, araw, blk);
    }
  }

  // ---- decode: LN -> GEMM -> drop CLS ----
  tr_k<<<dim3(24,24),256,0,stream>>>(W_dec, WdecT, 768,768, 768, 0);
  norm_k<<<M,256,0,stream>>>(t, g, ln_g, ln_b, 0, 1);
  gemm_bt<4,0><<<dim3(6,99),256,0,stream>>>(g, nullptr, WdecT, nullptr, out,
                                            M, 768, 768, 768, 768,
                                            b_dec, nullptr, nullptr, 0);
}